// Round 7
// baseline (515.292 us; speedup 1.0000x reference)
//
#include <hip/hip_runtime.h>

#define N_NODES 102000
#define D 128
#define L 12
#define E_EDGES 1000000
#define NEG_SLOPE 0.01f
#define NTILES (N_NODES / 16)   // 6375 exact (N % 16 == 0)

#define SCAN_CHUNK 1024
#define SCAN_BLOCKS ((N_NODES + SCAN_CHUNK - 1) / SCAN_CHUNK)  // 100

#define NXCD 8
#define RANGE (N_NODES / NXCD)   // 12750 exact

typedef __attribute__((ext_vector_type(8))) short bf16x8;
typedef __attribute__((ext_vector_type(4))) float f32x4;

__device__ __forceinline__ float b2f(unsigned short u) {
    union { float f; unsigned int i; } x; x.i = ((unsigned int)u) << 16; return x.f;
}
// round-to-nearest-even f32 -> bf16
__device__ __forceinline__ unsigned short f2b(float f) {
    unsigned int x = __float_as_uint(f);
    unsigned int r = (x + 0x7fffu + ((x >> 16) & 1u)) >> 16;
    return (unsigned short)r;
}

// ---------------------------------------------------------------------------
// 1) h[n] = sum_l word_emb[wids[n][l]] / lengths[n]   (f32 acc -> bf16 store)
//    XCD feature-sliced: group g = blockIdx&7 computes cols [g*16, g*16+16)
//    for ALL nodes -> per-XCD emb working set = 30001*64B = 1.9 MB (L2-fits).
//    thread = (node, float4-chunk within slice)
// ---------------------------------------------------------------------------
__global__ void pool_kernel(const int* __restrict__ wids,
                            const float* __restrict__ lengths,
                            const float* __restrict__ word_emb,
                            unsigned short* __restrict__ hb) {
    int g = blockIdx.x & (NXCD - 1);
    int idx = (blockIdx.x >> 3) * 256 + threadIdx.x;   // 0 .. N*4-1
    if (idx >= N_NODES * 4) return;
    int n = idx >> 2, q = idx & 3;
    int col0 = g * 16 + q * 4;
    const int* w = wids + n * L;
    float4 acc = make_float4(0.f, 0.f, 0.f, 0.f);
#pragma unroll
    for (int l = 0; l < L; ++l) {
        int wid = w[l];
        const float4 v = *reinterpret_cast<const float4*>(word_emb + (size_t)wid * D + col0);
        acc.x += v.x; acc.y += v.y; acc.z += v.z; acc.w += v.w;
    }
    float inv = 1.0f / lengths[n];
    ushort4 o;
    o.x = f2b(acc.x * inv); o.y = f2b(acc.y * inv);
    o.z = f2b(acc.z * inv); o.w = f2b(acc.w * inv);
    *reinterpret_cast<ushort4*>(hb + (size_t)n * D + col0) = o;
}

// ---------------------------------------------------------------------------
// 2) degree histogram, XCD-range-partitioned (dst ranges -> L2-local atomics)
// ---------------------------------------------------------------------------
#define DEGI_CHUNKS 256
__global__ void degi_kernel(const int* __restrict__ dst, int* __restrict__ deg) {
    int g = blockIdx.x & (NXCD - 1);
    int cb = blockIdx.x >> 3;              // 0..DEGI_CHUNKS-1
    int lo = g * RANGE, hi = lo + RANGE;
    const int stride = DEGI_CHUNKS * 256;
    for (int e = cb * 256 + threadIdx.x; e < E_EDGES; e += stride) {
        int d = dst[e];
        if (d >= lo && d < hi) atomicAdd(&deg[d], 1);
    }
}

// ---------------------------------------------------------------------------
// 3a) per-block local exclusive scan (1024 elems / block, 4 per thread)
// ---------------------------------------------------------------------------
__global__ __launch_bounds__(256)
void scan_local_kernel(const int* __restrict__ deg, int* __restrict__ row_ptr,
                       int* __restrict__ block_sums) {
    __shared__ int wsum[4];
    int t = threadIdx.x;
    int lane = t & 63, w = t >> 6;
    int base = blockIdx.x * SCAN_CHUNK + t * 4;
    int v0 = 0, v1 = 0, v2 = 0, v3 = 0;
    if (base + 3 < N_NODES) {
        int4 v = *reinterpret_cast<const int4*>(deg + base);
        v0 = v.x; v1 = v.y; v2 = v.z; v3 = v.w;
    } else {
        if (base + 0 < N_NODES) v0 = deg[base + 0];
        if (base + 1 < N_NODES) v1 = deg[base + 1];
        if (base + 2 < N_NODES) v2 = deg[base + 2];
        if (base + 3 < N_NODES) v3 = deg[base + 3];
    }
    int s = v0 + v1 + v2 + v3;
    int x = s;
#pragma unroll
    for (int off = 1; off < 64; off <<= 1) {
        int y = __shfl_up(x, off, 64);
        if (lane >= off) x += y;
    }
    if (lane == 63) wsum[w] = x;
    __syncthreads();
    int woff = 0;
#pragma unroll
    for (int i = 0; i < 4; ++i) if (i < w) woff += wsum[i];
    int excl = woff + (x - s);
    if (base + 0 < N_NODES) row_ptr[base + 0] = excl;
    if (base + 1 < N_NODES) row_ptr[base + 1] = excl + v0;
    if (base + 2 < N_NODES) row_ptr[base + 2] = excl + v0 + v1;
    if (base + 3 < N_NODES) row_ptr[base + 3] = excl + v0 + v1 + v2;
    __syncthreads();
    if (t == 255) block_sums[blockIdx.x] = woff + x;  // total of this block
}

// ---------------------------------------------------------------------------
// 3b) exclusive scan of the 100 block sums (one wave, 2 elems/lane)
// ---------------------------------------------------------------------------
__global__ __launch_bounds__(64)
void scan_blocks_kernel(int* __restrict__ block_sums, int* __restrict__ row_ptr) {
    int lane = threadIdx.x;
    int e0 = (2 * lane + 0 < SCAN_BLOCKS) ? block_sums[2 * lane + 0] : 0;
    int e1 = (2 * lane + 1 < SCAN_BLOCKS) ? block_sums[2 * lane + 1] : 0;
    int s = e0 + e1;
    int x = s;
#pragma unroll
    for (int off = 1; off < 64; off <<= 1) {
        int y = __shfl_up(x, off, 64);
        if (lane >= off) x += y;
    }
    int excl = x - s;
    if (2 * lane + 0 < SCAN_BLOCKS) block_sums[2 * lane + 0] = excl;
    if (2 * lane + 1 < SCAN_BLOCKS) block_sums[2 * lane + 1] = excl + e0;
    if (lane == 63) row_ptr[N_NODES] = x;   // total = E_EDGES
}

// ---------------------------------------------------------------------------
// 3c) add block offsets; emit final row_ptr and cursor copy
// ---------------------------------------------------------------------------
__global__ __launch_bounds__(256)
void scan_fixup_kernel(int* __restrict__ row_ptr, const int* __restrict__ block_sums,
                       int* __restrict__ cursor) {
    int base = blockIdx.x * SCAN_CHUNK + threadIdx.x * 4;
    int boff = block_sums[blockIdx.x];
#pragma unroll
    for (int j = 0; j < 4; ++j) {
        int i = base + j;
        if (i < N_NODES) {
            int v = row_ptr[i] + boff;
            row_ptr[i] = v;
            cursor[i] = v;
        }
    }
}

// ---------------------------------------------------------------------------
// 4) scatter edges into CSR slots, XCD-range-partitioned
// ---------------------------------------------------------------------------
#define SCAT_CHUNKS 512
__global__ void scatter_kernel(const int* __restrict__ src, const int* __restrict__ dst,
                               int* __restrict__ cursor, int* __restrict__ csr_src) {
    int g = blockIdx.x & (NXCD - 1);
    int cb = blockIdx.x >> 3;              // 0..SCAT_CHUNKS-1
    int lo = g * RANGE, hi = lo + RANGE;
    const int stride = SCAT_CHUNKS * 256;
    for (int e = cb * 256 + threadIdx.x; e < E_EDGES; e += stride) {
        int d = dst[e];
        if (d >= lo && d < hi) {
            int pos = atomicAdd(&cursor[d], 1);
            csr_src[pos] = src[e];
        }
    }
}

// ---------------------------------------------------------------------------
// 5) W -> bf16 MFMA B-fragment layout, once per layer.
// ---------------------------------------------------------------------------
__global__ void prep_w_kernel(const float* __restrict__ W1s, const float* __restrict__ W1n,
                              const float* __restrict__ W2s, const float* __restrict__ W2n,
                              uint4* __restrict__ wf1, uint4* __restrict__ wf2) {
    int tid = blockIdx.x * blockDim.x + threadIdx.x;   // 0..8191
    int layer = tid >> 12;
    int rem = tid & 4095;
    int ks = rem >> 9;
    int ct = (rem >> 6) & 7;
    int lane = rem & 63;
    const float* Ws = layer ? W2s : W1s;
    const float* Wn = layer ? W2n : W1n;
    uint4* outp = layer ? wf2 : wf1;
    int r0 = ks * 32 + (lane >> 4) * 8;
    int c = ct * 16 + (lane & 15);
    unsigned short e[8];
#pragma unroll
    for (int j = 0; j < 8; ++j) {
        int r = r0 + j;
        float v = (r < 128) ? Ws[r * 128 + c] : Wn[(r - 128) * 128 + c];
        e[j] = f2b(v);
    }
    uint4 o;
    o.x = (unsigned int)e[0] | ((unsigned int)e[1] << 16);
    o.y = (unsigned int)e[2] | ((unsigned int)e[3] << 16);
    o.z = (unsigned int)e[4] | ((unsigned int)e[5] << 16);
    o.w = (unsigned int)e[6] | ((unsigned int)e[7] << 16);
    outp[(ks * 8 + ct) * 64 + lane] = o;
}

// ---------------------------------------------------------------------------
// 6) gather-aggregate, XCD feature-sliced: group g handles cols
//    [g*16, g*16+16) for all nodes -> per-XCD h working set = 102000*32B =
//    3.3 MB (L2-fits). thread = (node, 16B half-slice); f32 acc, bf16 out.
//    Per-node reduction order identical to before (sequential p loop).
// ---------------------------------------------------------------------------
__global__ void gather_agg_kernel(const int* __restrict__ row_ptr,
                                  const int* __restrict__ csr_src,
                                  const unsigned short* __restrict__ hb,
                                  unsigned short* __restrict__ aggb) {
    int g = blockIdx.x & (NXCD - 1);
    int idx = (blockIdx.x >> 3) * 256 + threadIdx.x;   // 0 .. N*2-1
    if (idx >= N_NODES * 2) return;
    int n = idx >> 1, half = idx & 1;
    int col0 = g * 16 + half * 8;                      // 8 bf16 = 16 B
    int beg = row_ptr[n], end = row_ptr[n + 1];
    float acc[8];
#pragma unroll
    for (int j = 0; j < 8; ++j) acc[j] = 0.f;
    for (int p = beg; p < end; ++p) {
        int s = csr_src[p];
        uint4 v = *reinterpret_cast<const uint4*>(hb + (size_t)s * D + col0);
        acc[0] += b2f((unsigned short)(v.x & 0xffff)); acc[1] += b2f((unsigned short)(v.x >> 16));
        acc[2] += b2f((unsigned short)(v.y & 0xffff)); acc[3] += b2f((unsigned short)(v.y >> 16));
        acc[4] += b2f((unsigned short)(v.z & 0xffff)); acc[5] += b2f((unsigned short)(v.z >> 16));
        acc[6] += b2f((unsigned short)(v.w & 0xffff)); acc[7] += b2f((unsigned short)(v.w >> 16));
    }
    int dcount = end - beg;
    float inv = 1.0f / (float)(dcount > 1 ? dcount : 1);
    uint4 o;
    o.x = (unsigned int)f2b(acc[0] * inv) | ((unsigned int)f2b(acc[1] * inv) << 16);
    o.y = (unsigned int)f2b(acc[2] * inv) | ((unsigned int)f2b(acc[3] * inv) << 16);
    o.z = (unsigned int)f2b(acc[4] * inv) | ((unsigned int)f2b(acc[5] * inv) << 16);
    o.w = (unsigned int)f2b(acc[6] * inv) | ((unsigned int)f2b(acc[7] * inv) << 16);
    *reinterpret_cast<uint4*>(aggb + (size_t)n * D + col0) = o;
}

// ---------------------------------------------------------------------------
// 7) out = [h | agg] @ [Ws; Wn] + b  via mfma_f32_16x16x32_bf16.
//    4 waves/block, wave = one 16-row tile x 128 cols.
//    In-place (outp==hb, layer 1) is safe: each wave loads only its own 16
//    rows up-front; waves/blocks own disjoint rows. No __restrict__ (aliasing).
// ---------------------------------------------------------------------------
template <int RELU, typename OutT>
__global__ __launch_bounds__(256, 2)
void linear_mfma_kernel(const unsigned short* hb, const unsigned short* aggb,
                        const uint4* wfrag, const float* bias, OutT* outp) {
    __shared__ uint4 wlds[4096];   // 64 KB
    int t = threadIdx.x;
#pragma unroll
    for (int i = 0; i < 16; ++i) wlds[t + i * 256] = wfrag[t + i * 256];
    __syncthreads();
    int lane = t & 63, w = t >> 6;
    int rt = blockIdx.x * 4 + w;
    if (rt >= NTILES) return;      // no barriers after this point
    int row0 = rt * 16;
    int arow = row0 + (lane & 15);
    int koff = (lane >> 4) * 8;
    const unsigned short* hp = hb + (size_t)arow * D + koff;
    const unsigned short* ap = aggb + (size_t)arow * D + koff;
    bf16x8 a[8];
#pragma unroll
    for (int ks = 0; ks < 4; ++ks) a[ks] = *reinterpret_cast<const bf16x8*>(hp + ks * 32);
#pragma unroll
    for (int ks = 0; ks < 4; ++ks) a[4 + ks] = *reinterpret_cast<const bf16x8*>(ap + ks * 32);
    int crow = row0 + (lane >> 4) * 4;
    int ccol0 = lane & 15;
#pragma unroll
    for (int ct = 0; ct < 8; ++ct) {
        f32x4 acc = {0.f, 0.f, 0.f, 0.f};
#pragma unroll
        for (int ks = 0; ks < 8; ++ks) {
            bf16x8 b = *reinterpret_cast<const bf16x8*>(&wlds[(ks * 8 + ct) * 64 + lane]);
            acc = __builtin_amdgcn_mfma_f32_16x16x32_bf16(a[ks], b, acc, 0, 0, 0);
        }
        int col = ct * 16 + ccol0;
        float bv = bias[col];
#pragma unroll
        for (int i = 0; i < 4; ++i) {
            float v = acc[i] + bv;
            if (RELU) v = (v > 0.f) ? v : NEG_SLOPE * v;
            if constexpr (sizeof(OutT) == 2) {
                outp[(size_t)(crow + i) * D + col] = (OutT)f2b(v);
            } else {
                outp[(size_t)(crow + i) * D + col] = v;
            }
        }
    }
}

extern "C" void kernel_launch(void* const* d_in, const int* in_sizes, int n_in,
                              void* d_out, int out_size, void* d_ws, size_t ws_size,
                              hipStream_t stream) {
    const int*   wids     = (const int*)d_in[0];
    const float* lengths  = (const float*)d_in[1];
    const int*   src      = (const int*)d_in[2];
    const int*   dst      = (const int*)d_in[3];
    const float* word_emb = (const float*)d_in[4];
    const float* W1s      = (const float*)d_in[5];
    const float* W1n      = (const float*)d_in[6];
    const float* b1       = (const float*)d_in[7];
    const float* W2s      = (const float*)d_in[8];
    const float* W2n      = (const float*)d_in[9];
    const float* b2       = (const float*)d_in[10];

    // workspace layout (all 16B-aligned by construction)
    unsigned short* h0  = (unsigned short*)d_ws;               // N*D bf16
    unsigned short* agg = h0 + (size_t)N_NODES * D;            // N*D bf16
    uint4* wf1 = (uint4*)(agg + (size_t)N_NODES * D);          // 4096 uint4 (64 KB)
    uint4* wf2 = wf1 + 4096;                                   // 4096 uint4
    int* deg_i      = (int*)(wf2 + 4096);                      // N
    int* row_ptr    = deg_i + N_NODES;                         // N+1
    int* cursor     = row_ptr + (N_NODES + 1);                 // N
    int* block_sums = cursor + N_NODES;                        // SCAN_BLOCKS
    int* csr_src    = block_sums + ((SCAN_BLOCKS + 3) & ~3);   // E

    hipMemsetAsync(deg_i, 0, N_NODES * sizeof(int), stream);

    // pooled features (bf16), XCD feature-sliced
    const int POOL_BLKS_PER_G = (N_NODES * 4 + 255) / 256;     // 1594
    pool_kernel<<<NXCD * POOL_BLKS_PER_G, 256, 0, stream>>>(wids, lengths, word_emb, h0);

    // CSR build (shared by both layers)
    degi_kernel<<<NXCD * DEGI_CHUNKS, 256, 0, stream>>>(dst, deg_i);
    scan_local_kernel<<<SCAN_BLOCKS, 256, 0, stream>>>(deg_i, row_ptr, block_sums);
    scan_blocks_kernel<<<1, 64, 0, stream>>>(block_sums, row_ptr);
    scan_fixup_kernel<<<SCAN_BLOCKS, 256, 0, stream>>>(row_ptr, block_sums, cursor);
    scatter_kernel<<<NXCD * SCAT_CHUNKS, 256, 0, stream>>>(src, dst, cursor, csr_src);

    // W fragments (both layers)
    prep_w_kernel<<<32, 256, 0, stream>>>(W1s, W1n, W2s, W2n, wf1, wf2);

    const int GATHER_BLKS_PER_G = (N_NODES * 2 + 255) / 256;   // 797
    const int LIN_GRID = (NTILES + 3) / 4;  // 1594
    // layer 1 (in-place h0 -> h0)
    gather_agg_kernel<<<NXCD * GATHER_BLKS_PER_G, 256, 0, stream>>>(row_ptr, csr_src, h0, agg);
    linear_mfma_kernel<1, unsigned short><<<LIN_GRID, 256, 0, stream>>>(h0, agg, wf1, b1, h0);
    // layer 2 (f32 out)
    gather_agg_kernel<<<NXCD * GATHER_BLKS_PER_G, 256, 0, stream>>>(row_ptr, csr_src, h0, agg);
    linear_mfma_kernel<0, float><<<LIN_GRID, 256, 0, stream>>>(h0, agg, wf2, b2, (float*)d_out);
}

// Round 9
// 460.382 us; speedup vs baseline: 1.1193x; 1.1193x over previous
//
#include <hip/hip_runtime.h>

#define N_NODES 102000
#define D 128
#define L 12
#define E_EDGES 1000000
#define V_VOCAB 30001            // rows in word_emb (incl. padding row)
#define NEG_SLOPE 0.01f
#define NTILES (N_NODES / 16)    // 6375 exact

#define SCAN_CHUNK 1024
#define SCAN_BLOCKS ((N_NODES + SCAN_CHUNK - 1) / SCAN_CHUNK)  // 100

#define NXCD 8
#define RANGE (N_NODES / NXCD)   // 12750 exact
#define SLICE 16                 // feature cols per XCD slice (D/NXCD)
#define HS_STRIDE ((size_t)N_NODES * SLICE)     // bf16 elems per h/agg slice
#define WS_STRIDE ((size_t)V_VOCAB * SLICE)     // f32 elems per emb slice

typedef __attribute__((ext_vector_type(8))) short bf16x8;
typedef __attribute__((ext_vector_type(4))) float f32x4;
typedef __attribute__((ext_vector_type(4))) int i32x4;

__device__ __forceinline__ float b2f(unsigned short u) {
    union { float f; unsigned int i; } x; x.i = ((unsigned int)u) << 16; return x.f;
}
__device__ __forceinline__ unsigned short f2b(float f) {
    unsigned int x = __float_as_uint(f);
    unsigned int r = (x + 0x7fffu + ((x >> 16) & 1u)) >> 16;
    return (unsigned short)r;
}

// ---------------------------------------------------------------------------
// 0) word_emb [V][128] f32  ->  sliced ws [8][V][16] f32 (contiguous slices)
// ---------------------------------------------------------------------------
__global__ void emb_slice_kernel(const float* __restrict__ word_emb,
                                 float* __restrict__ ws) {
    int id = blockIdx.x * blockDim.x + threadIdx.x;
    if (id >= V_VOCAB * 32) return;          // 32 float4 per row
    int r = id >> 5, q = id & 31;
    float4 v = *reinterpret_cast<const float4*>(word_emb + (size_t)r * D + q * 4);
    int g = q >> 2;                          // slice
    int o = (q & 3) * 4;                     // offset in slice
    *reinterpret_cast<float4*>(ws + (size_t)g * WS_STRIDE + (size_t)r * SLICE + o) = v;
}

// ---------------------------------------------------------------------------
// 1) pool: h[n] = sum_l emb[wids[n][l]] / lengths[n]  (sliced in + sliced out)
//    group g = blockIdx&7 -> slice g only; per-XCD emb slice = 1.92 MB (L2).
//    wids read via non-temporal i32x4 (stream, read 8x across groups).
// ---------------------------------------------------------------------------
__global__ void pool_kernel(const int* __restrict__ wids,
                            const float* __restrict__ lengths,
                            const float* __restrict__ ws,
                            unsigned short* __restrict__ hs) {
    int g = blockIdx.x & (NXCD - 1);
    int idx = (blockIdx.x >> 3) * 256 + threadIdx.x;   // 0 .. N*4-1
    if (idx >= N_NODES * 4) return;
    int n = idx >> 2, q = idx & 3;
    const i32x4* wp = reinterpret_cast<const i32x4*>(wids + n * L);  // 48B-aligned
    i32x4 w0 = __builtin_nontemporal_load(wp + 0);
    i32x4 w1 = __builtin_nontemporal_load(wp + 1);
    i32x4 w2 = __builtin_nontemporal_load(wp + 2);
    int wid[L] = {w0.x, w0.y, w0.z, w0.w, w1.x, w1.y, w1.z, w1.w, w2.x, w2.y, w2.z, w2.w};
    const float* wsg = ws + (size_t)g * WS_STRIDE + q * 4;
    float4 acc = make_float4(0.f, 0.f, 0.f, 0.f);
#pragma unroll
    for (int l = 0; l < L; ++l) {
        const float4 v = *reinterpret_cast<const float4*>(wsg + (size_t)wid[l] * SLICE);
        acc.x += v.x; acc.y += v.y; acc.z += v.z; acc.w += v.w;
    }
    float inv = 1.0f / lengths[n];
    ushort4 o;
    o.x = f2b(acc.x * inv); o.y = f2b(acc.y * inv);
    o.z = f2b(acc.z * inv); o.w = f2b(acc.w * inv);
    *reinterpret_cast<ushort4*>(hs + (size_t)g * HS_STRIDE + (size_t)n * SLICE + q * 4) = o;
}

// ---------------------------------------------------------------------------
// 2) degree histogram, XCD-range-partitioned
// ---------------------------------------------------------------------------
#define DEGI_CHUNKS 256
__global__ void degi_kernel(const int* __restrict__ dst, int* __restrict__ deg) {
    int g = blockIdx.x & (NXCD - 1);
    int cb = blockIdx.x >> 3;
    int lo = g * RANGE, hi = lo + RANGE;
    const int stride = DEGI_CHUNKS * 256;
    for (int e = cb * 256 + threadIdx.x; e < E_EDGES; e += stride) {
        int d = dst[e];
        if (d >= lo && d < hi) atomicAdd(&deg[d], 1);
    }
}

// ---------------------------------------------------------------------------
// 3a) per-block local exclusive scan
// ---------------------------------------------------------------------------
__global__ __launch_bounds__(256)
void scan_local_kernel(const int* __restrict__ deg, int* __restrict__ row_ptr,
                       int* __restrict__ block_sums) {
    __shared__ int wsum[4];
    int t = threadIdx.x;
    int lane = t & 63, w = t >> 6;
    int base = blockIdx.x * SCAN_CHUNK + t * 4;
    int v0 = 0, v1 = 0, v2 = 0, v3 = 0;
    if (base + 3 < N_NODES) {
        int4 v = *reinterpret_cast<const int4*>(deg + base);
        v0 = v.x; v1 = v.y; v2 = v.z; v3 = v.w;
    } else {
        if (base + 0 < N_NODES) v0 = deg[base + 0];
        if (base + 1 < N_NODES) v1 = deg[base + 1];
        if (base + 2 < N_NODES) v2 = deg[base + 2];
        if (base + 3 < N_NODES) v3 = deg[base + 3];
    }
    int s = v0 + v1 + v2 + v3;
    int x = s;
#pragma unroll
    for (int off = 1; off < 64; off <<= 1) {
        int y = __shfl_up(x, off, 64);
        if (lane >= off) x += y;
    }
    if (lane == 63) wsum[w] = x;
    __syncthreads();
    int woff = 0;
#pragma unroll
    for (int i = 0; i < 4; ++i) if (i < w) woff += wsum[i];
    int excl = woff + (x - s);
    if (base + 0 < N_NODES) row_ptr[base + 0] = excl;
    if (base + 1 < N_NODES) row_ptr[base + 1] = excl + v0;
    if (base + 2 < N_NODES) row_ptr[base + 2] = excl + v0 + v1;
    if (base + 3 < N_NODES) row_ptr[base + 3] = excl + v0 + v1 + v2;
    __syncthreads();
    if (t == 255) block_sums[blockIdx.x] = woff + x;
}

// ---------------------------------------------------------------------------
// 3b) exclusive scan of block sums (one wave)
// ---------------------------------------------------------------------------
__global__ __launch_bounds__(64)
void scan_blocks_kernel(int* __restrict__ block_sums, int* __restrict__ row_ptr) {
    int lane = threadIdx.x;
    int e0 = (2 * lane + 0 < SCAN_BLOCKS) ? block_sums[2 * lane + 0] : 0;
    int e1 = (2 * lane + 1 < SCAN_BLOCKS) ? block_sums[2 * lane + 1] : 0;
    int s = e0 + e1;
    int x = s;
#pragma unroll
    for (int off = 1; off < 64; off <<= 1) {
        int y = __shfl_up(x, off, 64);
        if (lane >= off) x += y;
    }
    int excl = x - s;
    if (2 * lane + 0 < SCAN_BLOCKS) block_sums[2 * lane + 0] = excl;
    if (2 * lane + 1 < SCAN_BLOCKS) block_sums[2 * lane + 1] = excl + e0;
    if (lane == 63) row_ptr[N_NODES] = x;
}

// ---------------------------------------------------------------------------
// 3c) fixup + cursor copy
// ---------------------------------------------------------------------------
__global__ __launch_bounds__(256)
void scan_fixup_kernel(int* __restrict__ row_ptr, const int* __restrict__ block_sums,
                       int* __restrict__ cursor) {
    int base = blockIdx.x * SCAN_CHUNK + threadIdx.x * 4;
    int boff = block_sums[blockIdx.x];
#pragma unroll
    for (int j = 0; j < 4; ++j) {
        int i = base + j;
        if (i < N_NODES) {
            int v = row_ptr[i] + boff;
            row_ptr[i] = v;
            cursor[i] = v;
        }
    }
}

// ---------------------------------------------------------------------------
// 4) scatter edges into CSR slots, XCD-range-partitioned
// ---------------------------------------------------------------------------
#define SCAT_CHUNKS 512
__global__ void scatter_kernel(const int* __restrict__ src, const int* __restrict__ dst,
                               int* __restrict__ cursor, int* __restrict__ csr_src) {
    int g = blockIdx.x & (NXCD - 1);
    int cb = blockIdx.x >> 3;
    int lo = g * RANGE, hi = lo + RANGE;
    const int stride = SCAT_CHUNKS * 256;
    for (int e = cb * 256 + threadIdx.x; e < E_EDGES; e += stride) {
        int d = dst[e];
        if (d >= lo && d < hi) {
            int pos = atomicAdd(&cursor[d], 1);
            csr_src[pos] = src[e];
        }
    }
}

// ---------------------------------------------------------------------------
// 5) W -> bf16 MFMA B-fragment layout
// ---------------------------------------------------------------------------
__global__ void prep_w_kernel(const float* __restrict__ W1s, const float* __restrict__ W1n,
                              const float* __restrict__ W2s, const float* __restrict__ W2n,
                              uint4* __restrict__ wf1, uint4* __restrict__ wf2) {
    int tid = blockIdx.x * blockDim.x + threadIdx.x;   // 0..8191
    int layer = tid >> 12;
    int rem = tid & 4095;
    int ks = rem >> 9;
    int ct = (rem >> 6) & 7;
    int lane = rem & 63;
    const float* Ws = layer ? W2s : W1s;
    const float* Wn = layer ? W2n : W1n;
    uint4* outp = layer ? wf2 : wf1;
    int r0 = ks * 32 + (lane >> 4) * 8;
    int c = ct * 16 + (lane & 15);
    unsigned short e[8];
#pragma unroll
    for (int j = 0; j < 8; ++j) {
        int r = r0 + j;
        float v = (r < 128) ? Ws[r * 128 + c] : Wn[(r - 128) * 128 + c];
        e[j] = f2b(v);
    }
    uint4 o;
    o.x = (unsigned int)e[0] | ((unsigned int)e[1] << 16);
    o.y = (unsigned int)e[2] | ((unsigned int)e[3] << 16);
    o.z = (unsigned int)e[4] | ((unsigned int)e[5] << 16);
    o.w = (unsigned int)e[6] | ((unsigned int)e[7] << 16);
    outp[(ks * 8 + ct) * 64 + lane] = o;
}

// ---------------------------------------------------------------------------
// 6) gather-aggregate, sliced layout: group g reads/writes slice g only.
//    Per-XCD h slice = 3.26 MB contiguous -> L2-resident; csr_src is a
//    non-temporal stream so it doesn't evict the slice.
// ---------------------------------------------------------------------------
__global__ void gather_agg_kernel(const int* __restrict__ row_ptr,
                                  const int* __restrict__ csr_src,
                                  const unsigned short* __restrict__ hs,
                                  unsigned short* __restrict__ aggs) {
    int g = blockIdx.x & (NXCD - 1);
    int idx = (blockIdx.x >> 3) * 256 + threadIdx.x;   // 0 .. N*2-1
    if (idx >= N_NODES * 2) return;
    int n = idx >> 1, half = idx & 1;
    int c0 = half * 8;                                 // 8 bf16 = 16 B
    const unsigned short* hg = hs + (size_t)g * HS_STRIDE + c0;
    int beg = row_ptr[n], end = row_ptr[n + 1];
    float acc[8];
#pragma unroll
    for (int j = 0; j < 8; ++j) acc[j] = 0.f;
    for (int p = beg; p < end; ++p) {
        int s = __builtin_nontemporal_load(csr_src + p);
        uint4 v = *reinterpret_cast<const uint4*>(hg + (size_t)s * SLICE);
        acc[0] += b2f((unsigned short)(v.x & 0xffff)); acc[1] += b2f((unsigned short)(v.x >> 16));
        acc[2] += b2f((unsigned short)(v.y & 0xffff)); acc[3] += b2f((unsigned short)(v.y >> 16));
        acc[4] += b2f((unsigned short)(v.z & 0xffff)); acc[5] += b2f((unsigned short)(v.z >> 16));
        acc[6] += b2f((unsigned short)(v.w & 0xffff)); acc[7] += b2f((unsigned short)(v.w >> 16));
    }
    int dcount = end - beg;
    float inv = 1.0f / (float)(dcount > 1 ? dcount : 1);
    uint4 o;
    o.x = (unsigned int)f2b(acc[0] * inv) | ((unsigned int)f2b(acc[1] * inv) << 16);
    o.y = (unsigned int)f2b(acc[2] * inv) | ((unsigned int)f2b(acc[3] * inv) << 16);
    o.z = (unsigned int)f2b(acc[4] * inv) | ((unsigned int)f2b(acc[5] * inv) << 16);
    o.w = (unsigned int)f2b(acc[6] * inv) | ((unsigned int)f2b(acc[7] * inv) << 16);
    *reinterpret_cast<uint4*>(aggs + (size_t)g * HS_STRIDE + (size_t)n * SLICE + c0) = o;
}

// ---------------------------------------------------------------------------
// 7) out = [h | agg] @ [Ws; Wn] + b  via mfma_f32_16x16x32_bf16, sliced I/O.
//    Layer-1 writes bf16 sliced in-place (wave-local rows, loads complete
//    before stores); layer-2 writes plain f32 to d_out.
// ---------------------------------------------------------------------------
template <int RELU, typename OutT>
__global__ __launch_bounds__(256, 2)
void linear_mfma_kernel(const unsigned short* hs, const unsigned short* aggs,
                        const uint4* wfrag, const float* bias, OutT* outp) {
    __shared__ uint4 wlds[4096];   // 64 KB
    int t = threadIdx.x;
#pragma unroll
    for (int i = 0; i < 16; ++i) wlds[t + i * 256] = wfrag[t + i * 256];
    __syncthreads();
    int lane = t & 63, w = t >> 6;
    int rt = blockIdx.x * 4 + w;
    if (rt >= NTILES) return;      // no barriers after this point
    int row0 = rt * 16;
    int arow = row0 + (lane & 15);
    int koff = (lane >> 4) * 8;
    bf16x8 a[8];
#pragma unroll
    for (int ks = 0; ks < 4; ++ks) {
        int col = ks * 32 + koff;
        int gs = col >> 4, off = col & 15;
        a[ks] = *reinterpret_cast<const bf16x8*>(hs + (size_t)gs * HS_STRIDE + (size_t)arow * SLICE + off);
    }
#pragma unroll
    for (int ks = 0; ks < 4; ++ks) {
        int col = ks * 32 + koff;
        int gs = col >> 4, off = col & 15;
        a[4 + ks] = *reinterpret_cast<const bf16x8*>(aggs + (size_t)gs * HS_STRIDE + (size_t)arow * SLICE + off);
    }
    int crow = row0 + (lane >> 4) * 4;
    int ccol0 = lane & 15;
#pragma unroll
    for (int ct = 0; ct < 8; ++ct) {
        f32x4 acc = {0.f, 0.f, 0.f, 0.f};
#pragma unroll
        for (int ks = 0; ks < 8; ++ks) {
            bf16x8 b = *reinterpret_cast<const bf16x8*>(&wlds[(ks * 8 + ct) * 64 + lane]);
            acc = __builtin_amdgcn_mfma_f32_16x16x32_bf16(a[ks], b, acc, 0, 0, 0);
        }
        float bv = bias[ct * 16 + ccol0];
#pragma unroll
        for (int i = 0; i < 4; ++i) {
            float v = acc[i] + bv;
            if (RELU) v = (v > 0.f) ? v : NEG_SLOPE * v;
            if constexpr (sizeof(OutT) == 2) {
                // sliced bf16: slice = ct, offset = ccol0
                outp[(size_t)ct * HS_STRIDE + (size_t)(crow + i) * SLICE + ccol0] = (OutT)f2b(v);
            } else {
                outp[(size_t)(crow + i) * D + ct * 16 + ccol0] = v;
            }
        }
    }
}

extern "C" void kernel_launch(void* const* d_in, const int* in_sizes, int n_in,
                              void* d_out, int out_size, void* d_ws, size_t ws_size,
                              hipStream_t stream) {
    const int*   wids     = (const int*)d_in[0];
    const float* lengths  = (const float*)d_in[1];
    const int*   src      = (const int*)d_in[2];
    const int*   dst      = (const int*)d_in[3];
    const float* word_emb = (const float*)d_in[4];
    const float* W1s      = (const float*)d_in[5];
    const float* W1n      = (const float*)d_in[6];
    const float* b1       = (const float*)d_in[7];
    const float* W2s      = (const float*)d_in[8];
    const float* W2n      = (const float*)d_in[9];
    const float* b2       = (const float*)d_in[10];

    // workspace layout
    unsigned short* h0  = (unsigned short*)d_ws;               // N*D bf16 (sliced)
    unsigned short* agg = h0 + (size_t)N_NODES * D;            // N*D bf16 (sliced)
    uint4* wf1 = (uint4*)(agg + (size_t)N_NODES * D);          // 4096 uint4
    uint4* wf2 = wf1 + 4096;                                   // 4096 uint4
    int* deg_i      = (int*)(wf2 + 4096);                      // N
    int* row_ptr    = deg_i + N_NODES;                         // N+1
    int* cursor     = row_ptr + (N_NODES + 1);                 // N
    int* block_sums = cursor + N_NODES;                        // SCAN_BLOCKS
    int* csr_src    = block_sums + ((SCAN_BLOCKS + 3) & ~3);   // E

    // sliced word_emb staged in d_out (free until the final kernel; 15.4 MB of 52 MB)
    float* ws_emb = (float*)d_out;

    (void)hipMemsetAsync(deg_i, 0, N_NODES * sizeof(int), stream);

    emb_slice_kernel<<<(V_VOCAB * 32 + 255) / 256, 256, 0, stream>>>(word_emb, ws_emb);

    const int POOL_BLKS_PER_G = (N_NODES * 4 + 255) / 256;     // 1594
    pool_kernel<<<NXCD * POOL_BLKS_PER_G, 256, 0, stream>>>(wids, lengths, ws_emb, h0);

    // CSR build
    degi_kernel<<<NXCD * DEGI_CHUNKS, 256, 0, stream>>>(dst, deg_i);
    scan_local_kernel<<<SCAN_BLOCKS, 256, 0, stream>>>(deg_i, row_ptr, block_sums);
    scan_blocks_kernel<<<1, 64, 0, stream>>>(block_sums, row_ptr);
    scan_fixup_kernel<<<SCAN_BLOCKS, 256, 0, stream>>>(row_ptr, block_sums, cursor);
    scatter_kernel<<<NXCD * SCAT_CHUNKS, 256, 0, stream>>>(src, dst, cursor, csr_src);

    prep_w_kernel<<<32, 256, 0, stream>>>(W1s, W1n, W2s, W2n, wf1, wf2);

    const int GATHER_BLKS_PER_G = (N_NODES * 2 + 255) / 256;   // 797
    const int LIN_GRID = (NTILES + 3) / 4;                     // 1594
    // layer 1 (in-place h0 -> h0, sliced)
    gather_agg_kernel<<<NXCD * GATHER_BLKS_PER_G, 256, 0, stream>>>(row_ptr, csr_src, h0, agg);
    linear_mfma_kernel<1, unsigned short><<<LIN_GRID, 256, 0, stream>>>(h0, agg, wf1, b1, h0);
    // layer 2 (plain f32 out -> d_out, overwrites the staged emb slices)
    gather_agg_kernel<<<NXCD * GATHER_BLKS_PER_G, 256, 0, stream>>>(row_ptr, csr_src, h0, agg);
    linear_mfma_kernel<0, float><<<LIN_GRID, 256, 0, stream>>>(h0, agg, wf2, b2, (float*)d_out);
}

// Round 10
// 402.144 us; speedup vs baseline: 1.2814x; 1.1448x over previous
//
#include <hip/hip_runtime.h>

#define N_NODES 102000
#define D 128
#define L 12
#define E_EDGES 1000000
#define V_VOCAB 30001            // rows in word_emb (incl. padding row)
#define NEG_SLOPE 0.01f
#define NTILES (N_NODES / 16)    // 6375 exact

#define SCAN_CHUNK 1024
#define SCAN_BLOCKS ((N_NODES + SCAN_CHUNK - 1) / SCAN_CHUNK)  // 100

#define NXCD 8
#define RANGE (N_NODES / NXCD)   // 12750 exact
#define SLICE 16                 // feature cols per XCD slice (D/NXCD)
#define HS_STRIDE ((size_t)N_NODES * SLICE)     // bf16 elems per h/agg slice
#define WS_STRIDE ((size_t)V_VOCAB * SLICE)     // f32 elems per emb slice

typedef __attribute__((ext_vector_type(8))) short bf16x8;
typedef __attribute__((ext_vector_type(4))) float f32x4;
typedef __attribute__((ext_vector_type(4))) int i32x4;
typedef __attribute__((ext_vector_type(2))) unsigned int u32x2;
typedef __attribute__((ext_vector_type(4))) unsigned int u32x4;

__device__ __forceinline__ float b2f(unsigned short u) {
    union { float f; unsigned int i; } x; x.i = ((unsigned int)u) << 16; return x.f;
}
__device__ __forceinline__ unsigned short f2b(float f) {
    unsigned int x = __float_as_uint(f);
    unsigned int r = (x + 0x7fffu + ((x >> 16) & 1u)) >> 16;
    return (unsigned short)r;
}
__device__ __forceinline__ void acc8(float* acc, uint4 v) {
    acc[0] += b2f((unsigned short)(v.x & 0xffff)); acc[1] += b2f((unsigned short)(v.x >> 16));
    acc[2] += b2f((unsigned short)(v.y & 0xffff)); acc[3] += b2f((unsigned short)(v.y >> 16));
    acc[4] += b2f((unsigned short)(v.z & 0xffff)); acc[5] += b2f((unsigned short)(v.z >> 16));
    acc[6] += b2f((unsigned short)(v.w & 0xffff)); acc[7] += b2f((unsigned short)(v.w >> 16));
}

// ---------------------------------------------------------------------------
// 0) word_emb [V][128] f32  ->  sliced ws [8][V][16] f32 (contiguous slices)
// ---------------------------------------------------------------------------
__global__ void emb_slice_kernel(const float* __restrict__ word_emb,
                                 float* __restrict__ ws) {
    int id = blockIdx.x * blockDim.x + threadIdx.x;
    if (id >= V_VOCAB * 32) return;          // 32 float4 per row
    int r = id >> 5, q = id & 31;
    float4 v = *reinterpret_cast<const float4*>(word_emb + (size_t)r * D + q * 4);
    int g = q >> 2;                          // slice
    int o = (q & 3) * 4;                     // offset in slice
    *reinterpret_cast<float4*>(ws + (size_t)g * WS_STRIDE + (size_t)r * SLICE + o) = v;
}

// ---------------------------------------------------------------------------
// 1) pool: h[n] = sum_l emb[wids[n][l]] / lengths[n]  (sliced in + sliced out)
//    group g = blockIdx&7 -> slice g only; per-XCD emb slice = 1.92 MB (L2).
//    wids non-temporal (stream); hs output non-temporal (protect emb slice).
// ---------------------------------------------------------------------------
__global__ void pool_kernel(const int* __restrict__ wids,
                            const float* __restrict__ lengths,
                            const float* __restrict__ ws,
                            unsigned short* __restrict__ hs) {
    int g = blockIdx.x & (NXCD - 1);
    int idx = (blockIdx.x >> 3) * 256 + threadIdx.x;   // 0 .. N*4-1
    if (idx >= N_NODES * 4) return;
    int n = idx >> 2, q = idx & 3;
    const i32x4* wp = reinterpret_cast<const i32x4*>(wids + n * L);  // 48B-aligned
    i32x4 w0 = __builtin_nontemporal_load(wp + 0);
    i32x4 w1 = __builtin_nontemporal_load(wp + 1);
    i32x4 w2 = __builtin_nontemporal_load(wp + 2);
    int wid[L] = {w0.x, w0.y, w0.z, w0.w, w1.x, w1.y, w1.z, w1.w, w2.x, w2.y, w2.z, w2.w};
    const float* wsg = ws + (size_t)g * WS_STRIDE + q * 4;
    float4 acc = make_float4(0.f, 0.f, 0.f, 0.f);
#pragma unroll
    for (int l = 0; l < L; ++l) {
        const float4 v = *reinterpret_cast<const float4*>(wsg + (size_t)wid[l] * SLICE);
        acc.x += v.x; acc.y += v.y; acc.z += v.z; acc.w += v.w;
    }
    float inv = 1.0f / lengths[n];
    u32x2 o;
    o.x = (unsigned int)f2b(acc.x * inv) | ((unsigned int)f2b(acc.y * inv) << 16);
    o.y = (unsigned int)f2b(acc.z * inv) | ((unsigned int)f2b(acc.w * inv) << 16);
    __builtin_nontemporal_store(o,
        reinterpret_cast<u32x2*>(hs + (size_t)g * HS_STRIDE + (size_t)n * SLICE + q * 4));
}

// ---------------------------------------------------------------------------
// 2) degree histogram, XCD-range-partitioned
// ---------------------------------------------------------------------------
#define DEGI_CHUNKS 256
__global__ void degi_kernel(const int* __restrict__ dst, int* __restrict__ deg) {
    int g = blockIdx.x & (NXCD - 1);
    int cb = blockIdx.x >> 3;
    int lo = g * RANGE, hi = lo + RANGE;
    const int stride = DEGI_CHUNKS * 256;
    for (int e = cb * 256 + threadIdx.x; e < E_EDGES; e += stride) {
        int d = dst[e];
        if (d >= lo && d < hi) atomicAdd(&deg[d], 1);
    }
}

// ---------------------------------------------------------------------------
// 3a) per-block local exclusive scan
// ---------------------------------------------------------------------------
__global__ __launch_bounds__(256)
void scan_local_kernel(const int* __restrict__ deg, int* __restrict__ row_ptr,
                       int* __restrict__ block_sums) {
    __shared__ int wsum[4];
    int t = threadIdx.x;
    int lane = t & 63, w = t >> 6;
    int base = blockIdx.x * SCAN_CHUNK + t * 4;
    int v0 = 0, v1 = 0, v2 = 0, v3 = 0;
    if (base + 3 < N_NODES) {
        int4 v = *reinterpret_cast<const int4*>(deg + base);
        v0 = v.x; v1 = v.y; v2 = v.z; v3 = v.w;
    } else {
        if (base + 0 < N_NODES) v0 = deg[base + 0];
        if (base + 1 < N_NODES) v1 = deg[base + 1];
        if (base + 2 < N_NODES) v2 = deg[base + 2];
        if (base + 3 < N_NODES) v3 = deg[base + 3];
    }
    int s = v0 + v1 + v2 + v3;
    int x = s;
#pragma unroll
    for (int off = 1; off < 64; off <<= 1) {
        int y = __shfl_up(x, off, 64);
        if (lane >= off) x += y;
    }
    if (lane == 63) wsum[w] = x;
    __syncthreads();
    int woff = 0;
#pragma unroll
    for (int i = 0; i < 4; ++i) if (i < w) woff += wsum[i];
    int excl = woff + (x - s);
    if (base + 0 < N_NODES) row_ptr[base + 0] = excl;
    if (base + 1 < N_NODES) row_ptr[base + 1] = excl + v0;
    if (base + 2 < N_NODES) row_ptr[base + 2] = excl + v0 + v1;
    if (base + 3 < N_NODES) row_ptr[base + 3] = excl + v0 + v1 + v2;
    __syncthreads();
    if (t == 255) block_sums[blockIdx.x] = woff + x;
}

// ---------------------------------------------------------------------------
// 3b) exclusive scan of block sums (one wave)
// ---------------------------------------------------------------------------
__global__ __launch_bounds__(64)
void scan_blocks_kernel(int* __restrict__ block_sums, int* __restrict__ row_ptr) {
    int lane = threadIdx.x;
    int e0 = (2 * lane + 0 < SCAN_BLOCKS) ? block_sums[2 * lane + 0] : 0;
    int e1 = (2 * lane + 1 < SCAN_BLOCKS) ? block_sums[2 * lane + 1] : 0;
    int s = e0 + e1;
    int x = s;
#pragma unroll
    for (int off = 1; off < 64; off <<= 1) {
        int y = __shfl_up(x, off, 64);
        if (lane >= off) x += y;
    }
    int excl = x - s;
    if (2 * lane + 0 < SCAN_BLOCKS) block_sums[2 * lane + 0] = excl;
    if (2 * lane + 1 < SCAN_BLOCKS) block_sums[2 * lane + 1] = excl + e0;
    if (lane == 63) row_ptr[N_NODES] = x;
}

// ---------------------------------------------------------------------------
// 3c) fixup + cursor copy
// ---------------------------------------------------------------------------
__global__ __launch_bounds__(256)
void scan_fixup_kernel(int* __restrict__ row_ptr, const int* __restrict__ block_sums,
                       int* __restrict__ cursor) {
    int base = blockIdx.x * SCAN_CHUNK + threadIdx.x * 4;
    int boff = block_sums[blockIdx.x];
#pragma unroll
    for (int j = 0; j < 4; ++j) {
        int i = base + j;
        if (i < N_NODES) {
            int v = row_ptr[i] + boff;
            row_ptr[i] = v;
            cursor[i] = v;
        }
    }
}

// ---------------------------------------------------------------------------
// 4) scatter edges into CSR slots, XCD-range-partitioned
// ---------------------------------------------------------------------------
#define SCAT_CHUNKS 512
__global__ void scatter_kernel(const int* __restrict__ src, const int* __restrict__ dst,
                               int* __restrict__ cursor, int* __restrict__ csr_src) {
    int g = blockIdx.x & (NXCD - 1);
    int cb = blockIdx.x >> 3;
    int lo = g * RANGE, hi = lo + RANGE;
    const int stride = SCAT_CHUNKS * 256;
    for (int e = cb * 256 + threadIdx.x; e < E_EDGES; e += stride) {
        int d = dst[e];
        if (d >= lo && d < hi) {
            int pos = atomicAdd(&cursor[d], 1);
            csr_src[pos] = src[e];
        }
    }
}

// ---------------------------------------------------------------------------
// 5) W -> bf16 MFMA B-fragment layout
// ---------------------------------------------------------------------------
__global__ void prep_w_kernel(const float* __restrict__ W1s, const float* __restrict__ W1n,
                              const float* __restrict__ W2s, const float* __restrict__ W2n,
                              uint4* __restrict__ wf1, uint4* __restrict__ wf2) {
    int tid = blockIdx.x * blockDim.x + threadIdx.x;   // 0..8191
    int layer = tid >> 12;
    int rem = tid & 4095;
    int ks = rem >> 9;
    int ct = (rem >> 6) & 7;
    int lane = rem & 63;
    const float* Ws = layer ? W2s : W1s;
    const float* Wn = layer ? W2n : W1n;
    uint4* outp = layer ? wf2 : wf1;
    int r0 = ks * 32 + (lane >> 4) * 8;
    int c = ct * 16 + (lane & 15);
    unsigned short e[8];
#pragma unroll
    for (int j = 0; j < 8; ++j) {
        int r = r0 + j;
        float v = (r < 128) ? Ws[r * 128 + c] : Wn[(r - 128) * 128 + c];
        e[j] = f2b(v);
    }
    uint4 o;
    o.x = (unsigned int)e[0] | ((unsigned int)e[1] << 16);
    o.y = (unsigned int)e[2] | ((unsigned int)e[3] << 16);
    o.z = (unsigned int)e[4] | ((unsigned int)e[5] << 16);
    o.w = (unsigned int)e[6] | ((unsigned int)e[7] << 16);
    outp[(ks * 8 + ct) * 64 + lane] = o;
}

// ---------------------------------------------------------------------------
// 6) gather-aggregate, sliced layout + 4-edge ILP unroll.
//    Group g reads/writes slice g only (3.26 MB, L2-resident). csr_src via
//    NT loads; aggs via NT stores (don't thrash the h slice). 4 independent
//    h-row loads in flight per iteration -> ~4x less exposed latency.
// ---------------------------------------------------------------------------
__global__ void gather_agg_kernel(const int* __restrict__ row_ptr,
                                  const int* __restrict__ csr_src,
                                  const unsigned short* __restrict__ hs,
                                  unsigned short* __restrict__ aggs) {
    int g = blockIdx.x & (NXCD - 1);
    int idx = (blockIdx.x >> 3) * 256 + threadIdx.x;   // 0 .. N*2-1
    if (idx >= N_NODES * 2) return;
    int n = idx >> 1, half = idx & 1;
    int c0 = half * 8;                                 // 8 bf16 = 16 B
    const unsigned short* hg = hs + (size_t)g * HS_STRIDE + c0;
    int beg = row_ptr[n], end = row_ptr[n + 1];
    float acc[8];
#pragma unroll
    for (int j = 0; j < 8; ++j) acc[j] = 0.f;
    int p = beg;
    // prologue to 4-alignment (csr_src base is 16B-aligned)
    int pre = (4 - (p & 3)) & 3;
    int e1 = p + pre; if (e1 > end) e1 = end;
    for (; p < e1; ++p) {
        int s = __builtin_nontemporal_load(csr_src + p);
        acc8(acc, *reinterpret_cast<const uint4*>(hg + (size_t)s * SLICE));
    }
    // main: 4 independent gathers in flight
    for (; p + 4 <= end; p += 4) {
        i32x4 s4 = __builtin_nontemporal_load(
            reinterpret_cast<const i32x4*>(csr_src + p));
        uint4 v0 = *reinterpret_cast<const uint4*>(hg + (size_t)s4.x * SLICE);
        uint4 v1 = *reinterpret_cast<const uint4*>(hg + (size_t)s4.y * SLICE);
        uint4 v2 = *reinterpret_cast<const uint4*>(hg + (size_t)s4.z * SLICE);
        uint4 v3 = *reinterpret_cast<const uint4*>(hg + (size_t)s4.w * SLICE);
        acc8(acc, v0); acc8(acc, v1); acc8(acc, v2); acc8(acc, v3);
    }
    for (; p < end; ++p) {
        int s = __builtin_nontemporal_load(csr_src + p);
        acc8(acc, *reinterpret_cast<const uint4*>(hg + (size_t)s * SLICE));
    }
    int dcount = end - beg;
    float inv = 1.0f / (float)(dcount > 1 ? dcount : 1);
    u32x4 o;
    o.x = (unsigned int)f2b(acc[0] * inv) | ((unsigned int)f2b(acc[1] * inv) << 16);
    o.y = (unsigned int)f2b(acc[2] * inv) | ((unsigned int)f2b(acc[3] * inv) << 16);
    o.z = (unsigned int)f2b(acc[4] * inv) | ((unsigned int)f2b(acc[5] * inv) << 16);
    o.w = (unsigned int)f2b(acc[6] * inv) | ((unsigned int)f2b(acc[7] * inv) << 16);
    __builtin_nontemporal_store(o,
        reinterpret_cast<u32x4*>(aggs + (size_t)g * HS_STRIDE + (size_t)n * SLICE + c0));
}

// ---------------------------------------------------------------------------
// 7) out = [h | agg] @ [Ws; Wn] + b  via mfma_f32_16x16x32_bf16, sliced I/O.
//    Layer-1 writes bf16 sliced in-place (wave-local rows, loads complete
//    before stores); layer-2 writes plain f32 to d_out.
// ---------------------------------------------------------------------------
template <int RELU, typename OutT>
__global__ __launch_bounds__(256, 2)
void linear_mfma_kernel(const unsigned short* hs, const unsigned short* aggs,
                        const uint4* wfrag, const float* bias, OutT* outp) {
    __shared__ uint4 wlds[4096];   // 64 KB
    int t = threadIdx.x;
#pragma unroll
    for (int i = 0; i < 16; ++i) wlds[t + i * 256] = wfrag[t + i * 256];
    __syncthreads();
    int lane = t & 63, w = t >> 6;
    int rt = blockIdx.x * 4 + w;
    if (rt >= NTILES) return;      // no barriers after this point
    int row0 = rt * 16;
    int arow = row0 + (lane & 15);
    int koff = (lane >> 4) * 8;
    bf16x8 a[8];
#pragma unroll
    for (int ks = 0; ks < 4; ++ks) {
        int col = ks * 32 + koff;
        int gs = col >> 4, off = col & 15;
        a[ks] = *reinterpret_cast<const bf16x8*>(hs + (size_t)gs * HS_STRIDE + (size_t)arow * SLICE + off);
    }
#pragma unroll
    for (int ks = 0; ks < 4; ++ks) {
        int col = ks * 32 + koff;
        int gs = col >> 4, off = col & 15;
        a[4 + ks] = *reinterpret_cast<const bf16x8*>(aggs + (size_t)gs * HS_STRIDE + (size_t)arow * SLICE + off);
    }
    int crow = row0 + (lane >> 4) * 4;
    int ccol0 = lane & 15;
#pragma unroll
    for (int ct = 0; ct < 8; ++ct) {
        f32x4 acc = {0.f, 0.f, 0.f, 0.f};
#pragma unroll
        for (int ks = 0; ks < 8; ++ks) {
            bf16x8 b = *reinterpret_cast<const bf16x8*>(&wlds[(ks * 8 + ct) * 64 + lane]);
            acc = __builtin_amdgcn_mfma_f32_16x16x32_bf16(a[ks], b, acc, 0, 0, 0);
        }
        float bv = bias[ct * 16 + ccol0];
#pragma unroll
        for (int i = 0; i < 4; ++i) {
            float v = acc[i] + bv;
            if (RELU) v = (v > 0.f) ? v : NEG_SLOPE * v;
            if constexpr (sizeof(OutT) == 2) {
                outp[(size_t)ct * HS_STRIDE + (size_t)(crow + i) * SLICE + ccol0] = (OutT)f2b(v);
            } else {
                outp[(size_t)(crow + i) * D + ct * 16 + ccol0] = v;
            }
        }
    }
}

extern "C" void kernel_launch(void* const* d_in, const int* in_sizes, int n_in,
                              void* d_out, int out_size, void* d_ws, size_t ws_size,
                              hipStream_t stream) {
    const int*   wids     = (const int*)d_in[0];
    const float* lengths  = (const float*)d_in[1];
    const int*   src      = (const int*)d_in[2];
    const int*   dst      = (const int*)d_in[3];
    const float* word_emb = (const float*)d_in[4];
    const float* W1s      = (const float*)d_in[5];
    const float* W1n      = (const float*)d_in[6];
    const float* b1       = (const float*)d_in[7];
    const float* W2s      = (const float*)d_in[8];
    const float* W2n      = (const float*)d_in[9];
    const float* b2       = (const float*)d_in[10];

    // workspace layout
    unsigned short* h0  = (unsigned short*)d_ws;               // N*D bf16 (sliced)
    unsigned short* agg = h0 + (size_t)N_NODES * D;            // N*D bf16 (sliced)
    uint4* wf1 = (uint4*)(agg + (size_t)N_NODES * D);          // 4096 uint4
    uint4* wf2 = wf1 + 4096;                                   // 4096 uint4
    int* deg_i      = (int*)(wf2 + 4096);                      // N
    int* row_ptr    = deg_i + N_NODES;                         // N+1
    int* cursor     = row_ptr + (N_NODES + 1);                 // N
    int* block_sums = cursor + N_NODES;                        // SCAN_BLOCKS
    int* csr_src    = block_sums + ((SCAN_BLOCKS + 3) & ~3);   // E

    // sliced word_emb staged in d_out (free until the final kernel)
    float* ws_emb = (float*)d_out;

    (void)hipMemsetAsync(deg_i, 0, N_NODES * sizeof(int), stream);

    emb_slice_kernel<<<(V_VOCAB * 32 + 255) / 256, 256, 0, stream>>>(word_emb, ws_emb);

    const int POOL_BLKS_PER_G = (N_NODES * 4 + 255) / 256;     // 1594
    pool_kernel<<<NXCD * POOL_BLKS_PER_G, 256, 0, stream>>>(wids, lengths, ws_emb, h0);

    // CSR build
    degi_kernel<<<NXCD * DEGI_CHUNKS, 256, 0, stream>>>(dst, deg_i);
    scan_local_kernel<<<SCAN_BLOCKS, 256, 0, stream>>>(deg_i, row_ptr, block_sums);
    scan_blocks_kernel<<<1, 64, 0, stream>>>(block_sums, row_ptr);
    scan_fixup_kernel<<<SCAN_BLOCKS, 256, 0, stream>>>(row_ptr, block_sums, cursor);
    scatter_kernel<<<NXCD * SCAT_CHUNKS, 256, 0, stream>>>(src, dst, cursor, csr_src);

    prep_w_kernel<<<32, 256, 0, stream>>>(W1s, W1n, W2s, W2n, wf1, wf2);

    const int GATHER_BLKS_PER_G = (N_NODES * 2 + 255) / 256;   // 797
    const int LIN_GRID = (NTILES + 3) / 4;                     // 1594
    // layer 1 (in-place h0 -> h0, sliced)
    gather_agg_kernel<<<NXCD * GATHER_BLKS_PER_G, 256, 0, stream>>>(row_ptr, csr_src, h0, agg);
    linear_mfma_kernel<1, unsigned short><<<LIN_GRID, 256, 0, stream>>>(h0, agg, wf1, b1, h0);
    // layer 2 (plain f32 out -> d_out, overwrites the staged emb slices)
    gather_agg_kernel<<<NXCD * GATHER_BLKS_PER_G, 256, 0, stream>>>(row_ptr, csr_src, h0, agg);
    linear_mfma_kernel<0, float><<<LIN_GRID, 256, 0, stream>>>(h0, agg, wf2, b2, (float*)d_out);
}

// Round 11
// 309.458 us; speedup vs baseline: 1.6651x; 1.2995x over previous
//
#include <hip/hip_runtime.h>

#define N_NODES 102000
#define D 128
#define L 12
#define E_EDGES 1000000
#define V_VOCAB 30001            // rows in word_emb (incl. padding row)
#define NEG_SLOPE 0.01f
#define NTILES (N_NODES / 16)    // 6375 exact

#define SCAN_CHUNK 1024
#define SCAN_BLOCKS ((N_NODES + SCAN_CHUNK - 1) / SCAN_CHUNK)  // 100

#define NXCD 8
#define RANGE (N_NODES / NXCD)   // 12750 exact
#define SLICE 16                 // feature cols per XCD slice (D/NXCD)
#define HS_STRIDE ((size_t)N_NODES * SLICE)     // bf16 elems per sliced-h slice
#define WS_STRIDE ((size_t)V_VOCAB * SLICE)     // f32 elems per emb slice

typedef __attribute__((ext_vector_type(8))) short bf16x8;
typedef __attribute__((ext_vector_type(4))) float f32x4;
typedef __attribute__((ext_vector_type(4))) int i32x4;
typedef __attribute__((ext_vector_type(2))) unsigned int u32x2;
typedef __attribute__((ext_vector_type(4))) unsigned int u32x4;

__device__ __forceinline__ float b2f(unsigned short u) {
    union { float f; unsigned int i; } x; x.i = ((unsigned int)u) << 16; return x.f;
}
__device__ __forceinline__ unsigned short f2b(float f) {
    unsigned int x = __float_as_uint(f);
    unsigned int r = (x + 0x7fffu + ((x >> 16) & 1u)) >> 16;
    return (unsigned short)r;
}
__device__ __forceinline__ void acc8(float* acc, uint4 v) {
    acc[0] += b2f((unsigned short)(v.x & 0xffff)); acc[1] += b2f((unsigned short)(v.x >> 16));
    acc[2] += b2f((unsigned short)(v.y & 0xffff)); acc[3] += b2f((unsigned short)(v.y >> 16));
    acc[4] += b2f((unsigned short)(v.z & 0xffff)); acc[5] += b2f((unsigned short)(v.z >> 16));
    acc[6] += b2f((unsigned short)(v.w & 0xffff)); acc[7] += b2f((unsigned short)(v.w >> 16));
}

// ---------------------------------------------------------------------------
// 0) word_emb [V][128] f32  ->  sliced ws [8][V][16] f32 (contiguous slices)
// ---------------------------------------------------------------------------
__global__ void emb_slice_kernel(const float* __restrict__ word_emb,
                                 float* __restrict__ ws) {
    int id = blockIdx.x * blockDim.x + threadIdx.x;
    if (id >= V_VOCAB * 32) return;          // 32 float4 per row
    int r = id >> 5, q = id & 31;
    float4 v = *reinterpret_cast<const float4*>(word_emb + (size_t)r * D + q * 4);
    int g = q >> 2;                          // slice
    int o = (q & 3) * 4;                     // offset in slice
    *reinterpret_cast<float4*>(ws + (size_t)g * WS_STRIDE + (size_t)r * SLICE + o) = v;
}

// ---------------------------------------------------------------------------
// 1) pool (sliced): group g = blockIdx&7 computes slice g for all nodes.
//    Per-XCD emb slice = 1.92 MB -> L2-resident random gathers.
// ---------------------------------------------------------------------------
__global__ void pool_kernel(const int* __restrict__ wids,
                            const float* __restrict__ lengths,
                            const float* __restrict__ ws,
                            unsigned short* __restrict__ hs) {
    int g = blockIdx.x & (NXCD - 1);
    int idx = (blockIdx.x >> 3) * 256 + threadIdx.x;   // 0 .. N*4-1
    if (idx >= N_NODES * 4) return;
    int n = idx >> 2, q = idx & 3;
    const i32x4* wp = reinterpret_cast<const i32x4*>(wids + n * L);  // 48B-aligned
    i32x4 w0 = __builtin_nontemporal_load(wp + 0);
    i32x4 w1 = __builtin_nontemporal_load(wp + 1);
    i32x4 w2 = __builtin_nontemporal_load(wp + 2);
    int wid[L] = {w0.x, w0.y, w0.z, w0.w, w1.x, w1.y, w1.z, w1.w, w2.x, w2.y, w2.z, w2.w};
    const float* wsg = ws + (size_t)g * WS_STRIDE + q * 4;
    float4 acc = make_float4(0.f, 0.f, 0.f, 0.f);
#pragma unroll
    for (int l = 0; l < L; ++l) {
        const float4 v = *reinterpret_cast<const float4*>(wsg + (size_t)wid[l] * SLICE);
        acc.x += v.x; acc.y += v.y; acc.z += v.z; acc.w += v.w;
    }
    float inv = 1.0f / lengths[n];
    u32x2 o;
    o.x = (unsigned int)f2b(acc.x * inv) | ((unsigned int)f2b(acc.y * inv) << 16);
    o.y = (unsigned int)f2b(acc.z * inv) | ((unsigned int)f2b(acc.w * inv) << 16);
    __builtin_nontemporal_store(o,
        reinterpret_cast<u32x2*>(hs + (size_t)g * HS_STRIDE + (size_t)n * SLICE + q * 4));
}

// ---------------------------------------------------------------------------
// 1b) transpose sliced hs [8][N][16] -> interleaved h0 [N][128]
// ---------------------------------------------------------------------------
__global__ void transpose_h_kernel(const unsigned short* __restrict__ hs,
                                   unsigned short* __restrict__ h0) {
    int idx = blockIdx.x * 256 + threadIdx.x;   // 0 .. N*16-1
    int n = idx >> 4, q = idx & 15;             // q = 16B chunk (8 bf16)
    int g = q >> 1, off = (q & 1) * 8;
    uint4 v = *reinterpret_cast<const uint4*>(hs + (size_t)g * HS_STRIDE + (size_t)n * SLICE + off);
    *reinterpret_cast<uint4*>(h0 + (size_t)n * D + q * 8) = v;
}

// ---------------------------------------------------------------------------
// 2) degree histogram, XCD-range-partitioned
// ---------------------------------------------------------------------------
#define DEGI_CHUNKS 256
__global__ void degi_kernel(const int* __restrict__ dst, int* __restrict__ deg) {
    int g = blockIdx.x & (NXCD - 1);
    int cb = blockIdx.x >> 3;
    int lo = g * RANGE, hi = lo + RANGE;
    const int stride = DEGI_CHUNKS * 256;
    for (int e = cb * 256 + threadIdx.x; e < E_EDGES; e += stride) {
        int d = dst[e];
        if (d >= lo && d < hi) atomicAdd(&deg[d], 1);
    }
}

// ---------------------------------------------------------------------------
// 3a) per-block local exclusive scan
// ---------------------------------------------------------------------------
__global__ __launch_bounds__(256)
void scan_local_kernel(const int* __restrict__ deg, int* __restrict__ row_ptr,
                       int* __restrict__ block_sums) {
    __shared__ int wsum[4];
    int t = threadIdx.x;
    int lane = t & 63, w = t >> 6;
    int base = blockIdx.x * SCAN_CHUNK + t * 4;
    int v0 = 0, v1 = 0, v2 = 0, v3 = 0;
    if (base + 3 < N_NODES) {
        int4 v = *reinterpret_cast<const int4*>(deg + base);
        v0 = v.x; v1 = v.y; v2 = v.z; v3 = v.w;
    } else {
        if (base + 0 < N_NODES) v0 = deg[base + 0];
        if (base + 1 < N_NODES) v1 = deg[base + 1];
        if (base + 2 < N_NODES) v2 = deg[base + 2];
        if (base + 3 < N_NODES) v3 = deg[base + 3];
    }
    int s = v0 + v1 + v2 + v3;
    int x = s;
#pragma unroll
    for (int off = 1; off < 64; off <<= 1) {
        int y = __shfl_up(x, off, 64);
        if (lane >= off) x += y;
    }
    if (lane == 63) wsum[w] = x;
    __syncthreads();
    int woff = 0;
#pragma unroll
    for (int i = 0; i < 4; ++i) if (i < w) woff += wsum[i];
    int excl = woff + (x - s);
    if (base + 0 < N_NODES) row_ptr[base + 0] = excl;
    if (base + 1 < N_NODES) row_ptr[base + 1] = excl + v0;
    if (base + 2 < N_NODES) row_ptr[base + 2] = excl + v0 + v1;
    if (base + 3 < N_NODES) row_ptr[base + 3] = excl + v0 + v1 + v2;
    __syncthreads();
    if (t == 255) block_sums[blockIdx.x] = woff + x;
}

// ---------------------------------------------------------------------------
// 3b) exclusive scan of block sums (one wave)
// ---------------------------------------------------------------------------
__global__ __launch_bounds__(64)
void scan_blocks_kernel(int* __restrict__ block_sums, int* __restrict__ row_ptr) {
    int lane = threadIdx.x;
    int e0 = (2 * lane + 0 < SCAN_BLOCKS) ? block_sums[2 * lane + 0] : 0;
    int e1 = (2 * lane + 1 < SCAN_BLOCKS) ? block_sums[2 * lane + 1] : 0;
    int s = e0 + e1;
    int x = s;
#pragma unroll
    for (int off = 1; off < 64; off <<= 1) {
        int y = __shfl_up(x, off, 64);
        if (lane >= off) x += y;
    }
    int excl = x - s;
    if (2 * lane + 0 < SCAN_BLOCKS) block_sums[2 * lane + 0] = excl;
    if (2 * lane + 1 < SCAN_BLOCKS) block_sums[2 * lane + 1] = excl + e0;
    if (lane == 63) row_ptr[N_NODES] = x;
}

// ---------------------------------------------------------------------------
// 3c) fixup + cursor copy
// ---------------------------------------------------------------------------
__global__ __launch_bounds__(256)
void scan_fixup_kernel(int* __restrict__ row_ptr, const int* __restrict__ block_sums,
                       int* __restrict__ cursor) {
    int base = blockIdx.x * SCAN_CHUNK + threadIdx.x * 4;
    int boff = block_sums[blockIdx.x];
#pragma unroll
    for (int j = 0; j < 4; ++j) {
        int i = base + j;
        if (i < N_NODES) {
            int v = row_ptr[i] + boff;
            row_ptr[i] = v;
            cursor[i] = v;
        }
    }
}

// ---------------------------------------------------------------------------
// 4) scatter edges into CSR slots, XCD-range-partitioned
// ---------------------------------------------------------------------------
#define SCAT_CHUNKS 512
__global__ void scatter_kernel(const int* __restrict__ src, const int* __restrict__ dst,
                               int* __restrict__ cursor, int* __restrict__ csr_src) {
    int g = blockIdx.x & (NXCD - 1);
    int cb = blockIdx.x >> 3;
    int lo = g * RANGE, hi = lo + RANGE;
    const int stride = SCAT_CHUNKS * 256;
    for (int e = cb * 256 + threadIdx.x; e < E_EDGES; e += stride) {
        int d = dst[e];
        if (d >= lo && d < hi) {
            int pos = atomicAdd(&cursor[d], 1);
            csr_src[pos] = src[e];
        }
    }
}

// ---------------------------------------------------------------------------
// 5) W -> bf16 MFMA B-fragment layout
// ---------------------------------------------------------------------------
__global__ void prep_w_kernel(const float* __restrict__ W1s, const float* __restrict__ W1n,
                              const float* __restrict__ W2s, const float* __restrict__ W2n,
                              uint4* __restrict__ wf1, uint4* __restrict__ wf2) {
    int tid = blockIdx.x * blockDim.x + threadIdx.x;   // 0..8191
    int layer = tid >> 12;
    int rem = tid & 4095;
    int ks = rem >> 9;
    int ct = (rem >> 6) & 7;
    int lane = rem & 63;
    const float* Ws = layer ? W2s : W1s;
    const float* Wn = layer ? W2n : W1n;
    uint4* outp = layer ? wf2 : wf1;
    int r0 = ks * 32 + (lane >> 4) * 8;
    int c = ct * 16 + (lane & 15);
    unsigned short e[8];
#pragma unroll
    for (int j = 0; j < 8; ++j) {
        int r = r0 + j;
        float v = (r < 128) ? Ws[r * 128 + c] : Wn[(r - 128) * 128 + c];
        e[j] = f2b(v);
    }
    uint4 o;
    o.x = (unsigned int)e[0] | ((unsigned int)e[1] << 16);
    o.y = (unsigned int)e[2] | ((unsigned int)e[3] << 16);
    o.z = (unsigned int)e[4] | ((unsigned int)e[5] << 16);
    o.w = (unsigned int)e[6] | ((unsigned int)e[7] << 16);
    outp[(ks * 8 + ct) * 64 + lane] = o;
}

// ---------------------------------------------------------------------------
// 6) gather-aggregate, INTERLEAVED layout, 16 lanes/node, 4-edge ILP.
//    16 coalesced lanes read a full 256B row -> 4 fully-used line requests
//    per edge (half the requests of the sliced form, 2x line utilization).
// ---------------------------------------------------------------------------
__global__ void gather_agg_kernel(const int* __restrict__ row_ptr,
                                  const int* __restrict__ csr_src,
                                  const unsigned short* __restrict__ hI,
                                  unsigned short* __restrict__ aggI) {
    int idx = blockIdx.x * 256 + threadIdx.x;   // 0 .. N*16-1
    int n = idx >> 4, q = idx & 15;             // q = 16B chunk
    if (n >= N_NODES) return;
    const unsigned short* hq = hI + q * 8;
    int beg = row_ptr[n], end = row_ptr[n + 1];
    float acc[8];
#pragma unroll
    for (int j = 0; j < 8; ++j) acc[j] = 0.f;
    int p = beg;
    for (; p + 4 <= end; p += 4) {
        int s0 = csr_src[p + 0];
        int s1 = csr_src[p + 1];
        int s2 = csr_src[p + 2];
        int s3 = csr_src[p + 3];
        uint4 v0 = *reinterpret_cast<const uint4*>(hq + (size_t)s0 * D);
        uint4 v1 = *reinterpret_cast<const uint4*>(hq + (size_t)s1 * D);
        uint4 v2 = *reinterpret_cast<const uint4*>(hq + (size_t)s2 * D);
        uint4 v3 = *reinterpret_cast<const uint4*>(hq + (size_t)s3 * D);
        acc8(acc, v0); acc8(acc, v1); acc8(acc, v2); acc8(acc, v3);
    }
    for (; p < end; ++p) {
        int s = csr_src[p];
        acc8(acc, *reinterpret_cast<const uint4*>(hq + (size_t)s * D));
    }
    int dcount = end - beg;
    float inv = 1.0f / (float)(dcount > 1 ? dcount : 1);
    u32x4 o;
    o.x = (unsigned int)f2b(acc[0] * inv) | ((unsigned int)f2b(acc[1] * inv) << 16);
    o.y = (unsigned int)f2b(acc[2] * inv) | ((unsigned int)f2b(acc[3] * inv) << 16);
    o.z = (unsigned int)f2b(acc[4] * inv) | ((unsigned int)f2b(acc[5] * inv) << 16);
    o.w = (unsigned int)f2b(acc[6] * inv) | ((unsigned int)f2b(acc[7] * inv) << 16);
    __builtin_nontemporal_store(o,
        reinterpret_cast<u32x4*>(aggI + (size_t)n * D + q * 8));
}

// ---------------------------------------------------------------------------
// 7) out = [h | agg] @ [Ws; Wn] + b  via mfma_f32_16x16x32_bf16 (interleaved).
//    In-place (outp==hI, layer 1) safe: each wave loads only its own 16 rows
//    before any store; waves/blocks own disjoint rows. No __restrict__.
// ---------------------------------------------------------------------------
template <int RELU, typename OutT>
__global__ __launch_bounds__(256, 2)
void linear_mfma_kernel(const unsigned short* hI, const unsigned short* aggI,
                        const uint4* wfrag, const float* bias, OutT* outp) {
    __shared__ uint4 wlds[4096];   // 64 KB
    int t = threadIdx.x;
#pragma unroll
    for (int i = 0; i < 16; ++i) wlds[t + i * 256] = wfrag[t + i * 256];
    __syncthreads();
    int lane = t & 63, w = t >> 6;
    int rt = blockIdx.x * 4 + w;
    if (rt >= NTILES) return;      // no barriers after this point
    int row0 = rt * 16;
    int arow = row0 + (lane & 15);
    int koff = (lane >> 4) * 8;
    const unsigned short* hp = hI + (size_t)arow * D + koff;
    const unsigned short* ap = aggI + (size_t)arow * D + koff;
    bf16x8 a[8];
#pragma unroll
    for (int ks = 0; ks < 4; ++ks) a[ks] = *reinterpret_cast<const bf16x8*>(hp + ks * 32);
#pragma unroll
    for (int ks = 0; ks < 4; ++ks) a[4 + ks] = *reinterpret_cast<const bf16x8*>(ap + ks * 32);
    int crow = row0 + (lane >> 4) * 4;
    int ccol0 = lane & 15;
#pragma unroll
    for (int ct = 0; ct < 8; ++ct) {
        f32x4 acc = {0.f, 0.f, 0.f, 0.f};
#pragma unroll
        for (int ks = 0; ks < 8; ++ks) {
            bf16x8 b = *reinterpret_cast<const bf16x8*>(&wlds[(ks * 8 + ct) * 64 + lane]);
            acc = __builtin_amdgcn_mfma_f32_16x16x32_bf16(a[ks], b, acc, 0, 0, 0);
        }
        int col = ct * 16 + ccol0;
        float bv = bias[col];
#pragma unroll
        for (int i = 0; i < 4; ++i) {
            float v = acc[i] + bv;
            if (RELU) v = (v > 0.f) ? v : NEG_SLOPE * v;
            if constexpr (sizeof(OutT) == 2) {
                outp[(size_t)(crow + i) * D + col] = (OutT)f2b(v);
            } else {
                outp[(size_t)(crow + i) * D + col] = v;
            }
        }
    }
}

extern "C" void kernel_launch(void* const* d_in, const int* in_sizes, int n_in,
                              void* d_out, int out_size, void* d_ws, size_t ws_size,
                              hipStream_t stream) {
    const int*   wids     = (const int*)d_in[0];
    const float* lengths  = (const float*)d_in[1];
    const int*   src      = (const int*)d_in[2];
    const int*   dst      = (const int*)d_in[3];
    const float* word_emb = (const float*)d_in[4];
    const float* W1s      = (const float*)d_in[5];
    const float* W1n      = (const float*)d_in[6];
    const float* b1       = (const float*)d_in[7];
    const float* W2s      = (const float*)d_in[8];
    const float* W2n      = (const float*)d_in[9];
    const float* b2       = (const float*)d_in[10];

    // d_ws layout
    unsigned short* h0  = (unsigned short*)d_ws;               // N*D bf16 (interleaved)
    unsigned short* agg = h0 + (size_t)N_NODES * D;            // N*D bf16 (interleaved)
    uint4* wf1 = (uint4*)(agg + (size_t)N_NODES * D);          // 4096 uint4
    uint4* wf2 = wf1 + 4096;                                   // 4096 uint4
    int* deg_i      = (int*)(wf2 + 4096);                      // N
    int* row_ptr    = deg_i + N_NODES;                         // N+1
    int* cursor     = row_ptr + (N_NODES + 1);                 // N
    int* block_sums = cursor + N_NODES;                        // SCAN_BLOCKS
    int* csr_src    = block_sums + ((SCAN_BLOCKS + 3) & ~3);   // E

    // staged in d_out (free until the final layer-2 write):
    //   [0, 15.4MB): sliced emb; [15.4MB, 41.5MB): sliced h
    float* ws_emb = (float*)d_out;
    unsigned short* hs = (unsigned short*)(ws_emb + (size_t)NXCD * WS_STRIDE);

    (void)hipMemsetAsync(deg_i, 0, N_NODES * sizeof(int), stream);

    emb_slice_kernel<<<(V_VOCAB * 32 + 255) / 256, 256, 0, stream>>>(word_emb, ws_emb);

    const int POOL_BLKS_PER_G = (N_NODES * 4 + 255) / 256;     // 1594
    pool_kernel<<<NXCD * POOL_BLKS_PER_G, 256, 0, stream>>>(wids, lengths, ws_emb, hs);
    transpose_h_kernel<<<(N_NODES * 16) / 256, 256, 0, stream>>>(hs, h0);

    // CSR build
    degi_kernel<<<NXCD * DEGI_CHUNKS, 256, 0, stream>>>(dst, deg_i);
    scan_local_kernel<<<SCAN_BLOCKS, 256, 0, stream>>>(deg_i, row_ptr, block_sums);
    scan_blocks_kernel<<<1, 64, 0, stream>>>(block_sums, row_ptr);
    scan_fixup_kernel<<<SCAN_BLOCKS, 256, 0, stream>>>(row_ptr, block_sums, cursor);
    scatter_kernel<<<NXCD * SCAT_CHUNKS, 256, 0, stream>>>(src, dst, cursor, csr_src);

    prep_w_kernel<<<32, 256, 0, stream>>>(W1s, W1n, W2s, W2n, wf1, wf2);

    const int GATHER_GRID = (N_NODES * 16) / 256;              // 6375
    const int LIN_GRID = (NTILES + 3) / 4;                     // 1594
    // layer 1 (in-place h0 -> h0)
    gather_agg_kernel<<<GATHER_GRID, 256, 0, stream>>>(row_ptr, csr_src, h0, agg);
    linear_mfma_kernel<1, unsigned short><<<LIN_GRID, 256, 0, stream>>>(h0, agg, wf1, b1, h0);
    // layer 2 (f32 out -> d_out, overwrites staged emb/hs)
    gather_agg_kernel<<<GATHER_GRID, 256, 0, stream>>>(row_ptr, csr_src, h0, agg);
    linear_mfma_kernel<0, float><<<LIN_GRID, 256, 0, stream>>>(h0, agg, wf2, b2, (float*)d_out);
}

// Round 12
// 274.143 us; speedup vs baseline: 1.8796x; 1.1288x over previous
//
#include <hip/hip_runtime.h>

#define N_NODES 102000
#define D 128
#define L 12
#define E_EDGES 1000000
#define V_VOCAB 30001            // rows in word_emb (incl. padding row)
#define NEG_SLOPE 0.01f
#define NTILES (N_NODES / 16)    // 6375 exact

#define SCAN_CHUNK 1024
#define SCAN_BLOCKS ((N_NODES + SCAN_CHUNK - 1) / SCAN_CHUNK)  // 100

#define NXCD 8
#define RANGE (N_NODES / NXCD)   // 12750 exact

// pool slicing: 4 slices x 32 bf16 cols (one 64-B line per emb row-slice)
#define NSLC 4
#define SCOLS 32
#define WS2_STRIDE ((size_t)V_VOCAB * SCOLS)   // bf16 elems per emb slice

typedef __attribute__((ext_vector_type(8))) short bf16x8;
typedef __attribute__((ext_vector_type(4))) float f32x4;
typedef __attribute__((ext_vector_type(4))) int i32x4;
typedef __attribute__((ext_vector_type(4))) unsigned int u32x4;

__device__ __forceinline__ float b2f(unsigned short u) {
    union { float f; unsigned int i; } x; x.i = ((unsigned int)u) << 16; return x.f;
}
__device__ __forceinline__ unsigned short f2b(float f) {
    unsigned int x = __float_as_uint(f);
    unsigned int r = (x + 0x7fffu + ((x >> 16) & 1u)) >> 16;
    return (unsigned short)r;
}
__device__ __forceinline__ void acc8(float* acc, uint4 v) {
    acc[0] += b2f((unsigned short)(v.x & 0xffff)); acc[1] += b2f((unsigned short)(v.x >> 16));
    acc[2] += b2f((unsigned short)(v.y & 0xffff)); acc[3] += b2f((unsigned short)(v.y >> 16));
    acc[4] += b2f((unsigned short)(v.z & 0xffff)); acc[5] += b2f((unsigned short)(v.z >> 16));
    acc[6] += b2f((unsigned short)(v.w & 0xffff)); acc[7] += b2f((unsigned short)(v.w >> 16));
}

// ---------------------------------------------------------------------------
// 0) word_emb [V][128] f32 -> bf16 sliced ws [4][V][32] (64-B rows per slice)
// ---------------------------------------------------------------------------
__global__ void emb_slice_kernel(const float* __restrict__ word_emb,
                                 unsigned short* __restrict__ ws) {
    int id = blockIdx.x * blockDim.x + threadIdx.x;
    if (id >= V_VOCAB * 16) return;          // 16 chunks of 8 cols per row
    int r = id >> 4, q = id & 15;
    const float* p = word_emb + (size_t)r * D + q * 8;
    float4 v0 = *reinterpret_cast<const float4*>(p);
    float4 v1 = *reinterpret_cast<const float4*>(p + 4);
    u32x4 o;
    o.x = (unsigned int)f2b(v0.x) | ((unsigned int)f2b(v0.y) << 16);
    o.y = (unsigned int)f2b(v0.z) | ((unsigned int)f2b(v0.w) << 16);
    o.z = (unsigned int)f2b(v1.x) | ((unsigned int)f2b(v1.y) << 16);
    o.w = (unsigned int)f2b(v1.z) | ((unsigned int)f2b(v1.w) << 16);
    int s = q >> 2, inner = (q & 3) * 8;
    *reinterpret_cast<u32x4*>(ws + (size_t)s * WS2_STRIDE + (size_t)r * SCOLS + inner) = o;
}

// ---------------------------------------------------------------------------
// 1) pool: h0[n] = sum_l emb[wids[n][l]] / lengths[n]
//    4 slice-groups (g = blockIdx&3, slice on XCDs {g, g+4}); per-XCD emb
//    slice = 1.92 MB bf16 -> L2-resident; one 64-B line request per (row,
//    slice) -> 48 requests/node (half of before). Writes interleaved h0
//    directly (no transpose): 4 lanes cover 64 B contiguous.
// ---------------------------------------------------------------------------
__global__ void pool_kernel(const int* __restrict__ wids,
                            const float* __restrict__ lengths,
                            const unsigned short* __restrict__ ws,
                            unsigned short* __restrict__ h0) {
    int g = blockIdx.x & (NSLC - 1);
    int idx = (blockIdx.x >> 2) * 256 + threadIdx.x;   // 0 .. N*4-1
    if (idx >= N_NODES * 4) return;
    int n = idx >> 2, q = idx & 3;                     // q = 16B chunk in 64B slice row
    const i32x4* wp = reinterpret_cast<const i32x4*>(wids + n * L);  // 48B-aligned
    i32x4 w0 = __builtin_nontemporal_load(wp + 0);
    i32x4 w1 = __builtin_nontemporal_load(wp + 1);
    i32x4 w2 = __builtin_nontemporal_load(wp + 2);
    int wid[L] = {w0.x, w0.y, w0.z, w0.w, w1.x, w1.y, w1.z, w1.w, w2.x, w2.y, w2.z, w2.w};
    const unsigned short* wsg = ws + (size_t)g * WS2_STRIDE + q * 8;
    float acc[8];
#pragma unroll
    for (int j = 0; j < 8; ++j) acc[j] = 0.f;
#pragma unroll
    for (int l = 0; l < L; ++l) {
        uint4 v = *reinterpret_cast<const uint4*>(wsg + (size_t)wid[l] * SCOLS);
        acc8(acc, v);
    }
    float inv = 1.0f / lengths[n];
    u32x4 o;
    o.x = (unsigned int)f2b(acc[0] * inv) | ((unsigned int)f2b(acc[1] * inv) << 16);
    o.y = (unsigned int)f2b(acc[2] * inv) | ((unsigned int)f2b(acc[3] * inv) << 16);
    o.z = (unsigned int)f2b(acc[4] * inv) | ((unsigned int)f2b(acc[5] * inv) << 16);
    o.w = (unsigned int)f2b(acc[6] * inv) | ((unsigned int)f2b(acc[7] * inv) << 16);
    *reinterpret_cast<u32x4*>(h0 + (size_t)n * D + g * SCOLS + q * 8) = o;
}

// ---------------------------------------------------------------------------
// 2) degree histogram, XCD-range-partitioned
// ---------------------------------------------------------------------------
#define DEGI_CHUNKS 256
__global__ void degi_kernel(const int* __restrict__ dst, int* __restrict__ deg) {
    int g = blockIdx.x & (NXCD - 1);
    int cb = blockIdx.x >> 3;
    int lo = g * RANGE, hi = lo + RANGE;
    const int stride = DEGI_CHUNKS * 256;
    for (int e = cb * 256 + threadIdx.x; e < E_EDGES; e += stride) {
        int d = dst[e];
        if (d >= lo && d < hi) atomicAdd(&deg[d], 1);
    }
}

// ---------------------------------------------------------------------------
// 3a) per-block local exclusive scan
// ---------------------------------------------------------------------------
__global__ __launch_bounds__(256)
void scan_local_kernel(const int* __restrict__ deg, int* __restrict__ row_ptr,
                       int* __restrict__ block_sums) {
    __shared__ int wsum[4];
    int t = threadIdx.x;
    int lane = t & 63, w = t >> 6;
    int base = blockIdx.x * SCAN_CHUNK + t * 4;
    int v0 = 0, v1 = 0, v2 = 0, v3 = 0;
    if (base + 3 < N_NODES) {
        int4 v = *reinterpret_cast<const int4*>(deg + base);
        v0 = v.x; v1 = v.y; v2 = v.z; v3 = v.w;
    } else {
        if (base + 0 < N_NODES) v0 = deg[base + 0];
        if (base + 1 < N_NODES) v1 = deg[base + 1];
        if (base + 2 < N_NODES) v2 = deg[base + 2];
        if (base + 3 < N_NODES) v3 = deg[base + 3];
    }
    int s = v0 + v1 + v2 + v3;
    int x = s;
#pragma unroll
    for (int off = 1; off < 64; off <<= 1) {
        int y = __shfl_up(x, off, 64);
        if (lane >= off) x += y;
    }
    if (lane == 63) wsum[w] = x;
    __syncthreads();
    int woff = 0;
#pragma unroll
    for (int i = 0; i < 4; ++i) if (i < w) woff += wsum[i];
    int excl = woff + (x - s);
    if (base + 0 < N_NODES) row_ptr[base + 0] = excl;
    if (base + 1 < N_NODES) row_ptr[base + 1] = excl + v0;
    if (base + 2 < N_NODES) row_ptr[base + 2] = excl + v0 + v1;
    if (base + 3 < N_NODES) row_ptr[base + 3] = excl + v0 + v1 + v2;
    __syncthreads();
    if (t == 255) block_sums[blockIdx.x] = woff + x;
}

// ---------------------------------------------------------------------------
// 3b) exclusive scan of block sums (one wave)
// ---------------------------------------------------------------------------
__global__ __launch_bounds__(64)
void scan_blocks_kernel(int* __restrict__ block_sums, int* __restrict__ row_ptr) {
    int lane = threadIdx.x;
    int e0 = (2 * lane + 0 < SCAN_BLOCKS) ? block_sums[2 * lane + 0] : 0;
    int e1 = (2 * lane + 1 < SCAN_BLOCKS) ? block_sums[2 * lane + 1] : 0;
    int s = e0 + e1;
    int x = s;
#pragma unroll
    for (int off = 1; off < 64; off <<= 1) {
        int y = __shfl_up(x, off, 64);
        if (lane >= off) x += y;
    }
    int excl = x - s;
    if (2 * lane + 0 < SCAN_BLOCKS) block_sums[2 * lane + 0] = excl;
    if (2 * lane + 1 < SCAN_BLOCKS) block_sums[2 * lane + 1] = excl + e0;
    if (lane == 63) row_ptr[N_NODES] = x;
}

// ---------------------------------------------------------------------------
// 3c) fixup + cursor copy
// ---------------------------------------------------------------------------
__global__ __launch_bounds__(256)
void scan_fixup_kernel(int* __restrict__ row_ptr, const int* __restrict__ block_sums,
                       int* __restrict__ cursor) {
    int base = blockIdx.x * SCAN_CHUNK + threadIdx.x * 4;
    int boff = block_sums[blockIdx.x];
#pragma unroll
    for (int j = 0; j < 4; ++j) {
        int i = base + j;
        if (i < N_NODES) {
            int v = row_ptr[i] + boff;
            row_ptr[i] = v;
            cursor[i] = v;
        }
    }
}

// ---------------------------------------------------------------------------
// 4) scatter edges into CSR slots, XCD-range-partitioned
// ---------------------------------------------------------------------------
#define SCAT_CHUNKS 512
__global__ void scatter_kernel(const int* __restrict__ src, const int* __restrict__ dst,
                               int* __restrict__ cursor, int* __restrict__ csr_src) {
    int g = blockIdx.x & (NXCD - 1);
    int cb = blockIdx.x >> 3;
    int lo = g * RANGE, hi = lo + RANGE;
    const int stride = SCAT_CHUNKS * 256;
    for (int e = cb * 256 + threadIdx.x; e < E_EDGES; e += stride) {
        int d = dst[e];
        if (d >= lo && d < hi) {
            int pos = atomicAdd(&cursor[d], 1);
            csr_src[pos] = src[e];
        }
    }
}

// ---------------------------------------------------------------------------
// 5) W -> bf16 MFMA B-fragment layout
// ---------------------------------------------------------------------------
__global__ void prep_w_kernel(const float* __restrict__ W1s, const float* __restrict__ W1n,
                              const float* __restrict__ W2s, const float* __restrict__ W2n,
                              uint4* __restrict__ wf1, uint4* __restrict__ wf2) {
    int tid = blockIdx.x * blockDim.x + threadIdx.x;   // 0..8191
    int layer = tid >> 12;
    int rem = tid & 4095;
    int ks = rem >> 9;
    int ct = (rem >> 6) & 7;
    int lane = rem & 63;
    const float* Ws = layer ? W2s : W1s;
    const float* Wn = layer ? W2n : W1n;
    uint4* outp = layer ? wf2 : wf1;
    int r0 = ks * 32 + (lane >> 4) * 8;
    int c = ct * 16 + (lane & 15);
    unsigned short e[8];
#pragma unroll
    for (int j = 0; j < 8; ++j) {
        int r = r0 + j;
        float v = (r < 128) ? Ws[r * 128 + c] : Wn[(r - 128) * 128 + c];
        e[j] = f2b(v);
    }
    uint4 o;
    o.x = (unsigned int)e[0] | ((unsigned int)e[1] << 16);
    o.y = (unsigned int)e[2] | ((unsigned int)e[3] << 16);
    o.z = (unsigned int)e[4] | ((unsigned int)e[5] << 16);
    o.w = (unsigned int)e[6] | ((unsigned int)e[7] << 16);
    outp[(ks * 8 + ct) * 64 + lane] = o;
}

// ---------------------------------------------------------------------------
// 6) gather-aggregate, interleaved layout, 16 lanes/node, 4-edge ILP.
//    Plain (cached) loads/stores: csr is reused by layer 2, agg is consumed
//    immediately by the linear -- let L2/L3 keep them.
// ---------------------------------------------------------------------------
__global__ void gather_agg_kernel(const int* __restrict__ row_ptr,
                                  const int* __restrict__ csr_src,
                                  const unsigned short* __restrict__ hI,
                                  unsigned short* __restrict__ aggI) {
    int idx = blockIdx.x * 256 + threadIdx.x;   // 0 .. N*16-1
    int n = idx >> 4, q = idx & 15;             // q = 16B chunk
    if (n >= N_NODES) return;
    const unsigned short* hq = hI + q * 8;
    int beg = row_ptr[n], end = row_ptr[n + 1];
    float acc[8];
#pragma unroll
    for (int j = 0; j < 8; ++j) acc[j] = 0.f;
    int p = beg;
    for (; p + 4 <= end; p += 4) {
        int s0 = csr_src[p + 0];
        int s1 = csr_src[p + 1];
        int s2 = csr_src[p + 2];
        int s3 = csr_src[p + 3];
        uint4 v0 = *reinterpret_cast<const uint4*>(hq + (size_t)s0 * D);
        uint4 v1 = *reinterpret_cast<const uint4*>(hq + (size_t)s1 * D);
        uint4 v2 = *reinterpret_cast<const uint4*>(hq + (size_t)s2 * D);
        uint4 v3 = *reinterpret_cast<const uint4*>(hq + (size_t)s3 * D);
        acc8(acc, v0); acc8(acc, v1); acc8(acc, v2); acc8(acc, v3);
    }
    for (; p < end; ++p) {
        int s = csr_src[p];
        acc8(acc, *reinterpret_cast<const uint4*>(hq + (size_t)s * D));
    }
    int dcount = end - beg;
    float inv = 1.0f / (float)(dcount > 1 ? dcount : 1);
    u32x4 o;
    o.x = (unsigned int)f2b(acc[0] * inv) | ((unsigned int)f2b(acc[1] * inv) << 16);
    o.y = (unsigned int)f2b(acc[2] * inv) | ((unsigned int)f2b(acc[3] * inv) << 16);
    o.z = (unsigned int)f2b(acc[4] * inv) | ((unsigned int)f2b(acc[5] * inv) << 16);
    o.w = (unsigned int)f2b(acc[6] * inv) | ((unsigned int)f2b(acc[7] * inv) << 16);
    *reinterpret_cast<u32x4*>(aggI + (size_t)n * D + q * 8) = o;
}

// ---------------------------------------------------------------------------
// 7) out = [h | agg] @ [Ws; Wn] + b  via mfma_f32_16x16x32_bf16 (interleaved).
//    In-place (outp==hI, layer 1) safe: each wave loads only its own 16 rows
//    before any store; waves/blocks own disjoint rows. No __restrict__.
// ---------------------------------------------------------------------------
template <int RELU, typename OutT>
__global__ __launch_bounds__(256, 2)
void linear_mfma_kernel(const unsigned short* hI, const unsigned short* aggI,
                        const uint4* wfrag, const float* bias, OutT* outp) {
    __shared__ uint4 wlds[4096];   // 64 KB
    int t = threadIdx.x;
#pragma unroll
    for (int i = 0; i < 16; ++i) wlds[t + i * 256] = wfrag[t + i * 256];
    __syncthreads();
    int lane = t & 63, w = t >> 6;
    int rt = blockIdx.x * 4 + w;
    if (rt >= NTILES) return;      // no barriers after this point
    int row0 = rt * 16;
    int arow = row0 + (lane & 15);
    int koff = (lane >> 4) * 8;
    const unsigned short* hp = hI + (size_t)arow * D + koff;
    const unsigned short* ap = aggI + (size_t)arow * D + koff;
    bf16x8 a[8];
#pragma unroll
    for (int ks = 0; ks < 4; ++ks) a[ks] = *reinterpret_cast<const bf16x8*>(hp + ks * 32);
#pragma unroll
    for (int ks = 0; ks < 4; ++ks) a[4 + ks] = *reinterpret_cast<const bf16x8*>(ap + ks * 32);
    int crow = row0 + (lane >> 4) * 4;
    int ccol0 = lane & 15;
#pragma unroll
    for (int ct = 0; ct < 8; ++ct) {
        f32x4 acc = {0.f, 0.f, 0.f, 0.f};
#pragma unroll
        for (int ks = 0; ks < 8; ++ks) {
            bf16x8 b = *reinterpret_cast<const bf16x8*>(&wlds[(ks * 8 + ct) * 64 + lane]);
            acc = __builtin_amdgcn_mfma_f32_16x16x32_bf16(a[ks], b, acc, 0, 0, 0);
        }
        int col = ct * 16 + ccol0;
        float bv = bias[col];
#pragma unroll
        for (int i = 0; i < 4; ++i) {
            float v = acc[i] + bv;
            if (RELU) v = (v > 0.f) ? v : NEG_SLOPE * v;
            if constexpr (sizeof(OutT) == 2) {
                outp[(size_t)(crow + i) * D + col] = (OutT)f2b(v);
            } else {
                outp[(size_t)(crow + i) * D + col] = v;
            }
        }
    }
}

extern "C" void kernel_launch(void* const* d_in, const int* in_sizes, int n_in,
                              void* d_out, int out_size, void* d_ws, size_t ws_size,
                              hipStream_t stream) {
    const int*   wids     = (const int*)d_in[0];
    const float* lengths  = (const float*)d_in[1];
    const int*   src      = (const int*)d_in[2];
    const int*   dst      = (const int*)d_in[3];
    const float* word_emb = (const float*)d_in[4];
    const float* W1s      = (const float*)d_in[5];
    const float* W1n      = (const float*)d_in[6];
    const float* b1       = (const float*)d_in[7];
    const float* W2s      = (const float*)d_in[8];
    const float* W2n      = (const float*)d_in[9];
    const float* b2       = (const float*)d_in[10];

    // d_ws layout
    unsigned short* h0  = (unsigned short*)d_ws;               // N*D bf16 (interleaved)
    unsigned short* agg = h0 + (size_t)N_NODES * D;            // N*D bf16 (interleaved)
    uint4* wf1 = (uint4*)(agg + (size_t)N_NODES * D);          // 4096 uint4
    uint4* wf2 = wf1 + 4096;                                   // 4096 uint4
    int* deg_i      = (int*)(wf2 + 4096);                      // N
    int* row_ptr    = deg_i + N_NODES;                         // N+1
    int* cursor     = row_ptr + (N_NODES + 1);                 // N
    int* block_sums = cursor + N_NODES;                        // SCAN_BLOCKS
    int* csr_src    = block_sums + ((SCAN_BLOCKS + 3) & ~3);   // E

    // bf16 sliced emb staged in d_out (7.7 MB of 52 MB; free until final write)
    unsigned short* ws_emb = (unsigned short*)d_out;

    (void)hipMemsetAsync(deg_i, 0, N_NODES * sizeof(int), stream);

    emb_slice_kernel<<<(V_VOCAB * 16 + 255) / 256, 256, 0, stream>>>(word_emb, ws_emb);

    const int POOL_BLKS_PER_G = (N_NODES * 4 + 255) / 256;     // 1594
    pool_kernel<<<NSLC * POOL_BLKS_PER_G, 256, 0, stream>>>(wids, lengths, ws_emb, h0);

    // CSR build
    degi_kernel<<<NXCD * DEGI_CHUNKS, 256, 0, stream>>>(dst, deg_i);
    scan_local_kernel<<<SCAN_BLOCKS, 256, 0, stream>>>(deg_i, row_ptr, block_sums);
    scan_blocks_kernel<<<1, 64, 0, stream>>>(block_sums, row_ptr);
    scan_fixup_kernel<<<SCAN_BLOCKS, 256, 0, stream>>>(row_ptr, block_sums, cursor);
    scatter_kernel<<<NXCD * SCAT_CHUNKS, 256, 0, stream>>>(src, dst, cursor, csr_src);

    prep_w_kernel<<<32, 256, 0, stream>>>(W1s, W1n, W2s, W2n, wf1, wf2);

    const int GATHER_GRID = (N_NODES * 16) / 256;              // 6375
    const int LIN_GRID = (NTILES + 3) / 4;                     // 1594
    // layer 1 (in-place h0 -> h0)
    gather_agg_kernel<<<GATHER_GRID, 256, 0, stream>>>(row_ptr, csr_src, h0, agg);
    linear_mfma_kernel<1, unsigned short><<<LIN_GRID, 256, 0, stream>>>(h0, agg, wf1, b1, h0);
    // layer 2 (f32 out -> d_out, overwrites staged emb)
    gather_agg_kernel<<<GATHER_GRID, 256, 0, stream>>>(row_ptr, csr_src, h0, agg);
    linear_mfma_kernel<0, float><<<LIN_GRID, 256, 0, stream>>>(h0, agg, wf2, b2, (float*)d_out);
}